// Round 1
// baseline (3616.398 us; speedup 1.0000x reference)
//
#include <hip/hip_runtime.h>
#include <hip/hip_bf16.h>
#include <stdint.h>

#define DIMQ   1024
#define NHEADS 16
#define HD     64
#define NEXP   8
#define DFF    4096
#define NTOK   8192
#define TSEQ   1024
#define BATCH  8

typedef unsigned short u16;
typedef unsigned int   u32;
typedef __attribute__((ext_vector_type(8))) short bf16x8;
typedef __attribute__((ext_vector_type(4))) float f32x4;

__device__ __forceinline__ float bf_lo(u32 w) { return __uint_as_float(w << 16); }
__device__ __forceinline__ float bf_hi(u32 w) { return __uint_as_float(w & 0xffff0000u); }
__device__ __forceinline__ u16 f2bf(float f) {
  u32 x = __float_as_uint(f);
  return (u16)((x + 0x7fffu + ((x >> 16) & 1u)) >> 16);
}

// ---------------- convert f32 -> bf16 ----------------
__global__ __launch_bounds__(256) void cvt_f32_bf16(const float* __restrict__ in,
                                                    u16* __restrict__ out, int n) {
  int i = (blockIdx.x * 256 + threadIdx.x) * 4;
  if (i >= n) return;
  float4 v = *(const float4*)(in + i);
  ushort4 o;
  o.x = f2bf(v.x); o.y = f2bf(v.y); o.z = f2bf(v.z); o.w = f2bf(v.w);
  *(ushort4*)(out + i) = o;
}

// ---------------- batched transpose f32[R][C] -> bf16[C][R] ----------------
__global__ __launch_bounds__(256) void transpose_f32_bf16(
    const float* __restrict__ in, u16* __restrict__ out, int R, int C) {
  __shared__ float tile[32][33];
  size_t base = (size_t)blockIdx.z * (size_t)R * (size_t)C;
  int tx = threadIdx.x & 31, ty = threadIdx.x >> 5;
  int c = blockIdx.x * 32 + tx;
#pragma unroll
  for (int i = 0; i < 4; i++) {
    int r = blockIdx.y * 32 + ty + i * 8;
    tile[ty + i * 8][tx] = in[base + (size_t)r * C + c];
  }
  __syncthreads();
  int rr = blockIdx.y * 32 + tx;
#pragma unroll
  for (int i = 0; i < 4; i++) {
    int cc = blockIdx.x * 32 + ty + i * 8;
    out[base + (size_t)cc * R + rr] = f2bf(tile[tx][ty + i * 8]);
  }
}

// ---------------- shared MFMA GEMM core: C[M,N] = A[M,K] * Bt[N,K]^T + bias ----------------
// 128x128 tile, BK=32, 256 threads (4 waves, 2x2), 4x4 fragments of 16x16x32 per wave.
template <bool GATHER, bool RELU>
__device__ __forceinline__ void gemm_core(
    const u16* __restrict__ A, const u16* __restrict__ Bt,
    const float* __restrict__ bias, u16* __restrict__ C,
    int M, int N, int K, const int* __restrict__ gidx) {
  __shared__ u16 As[128 * 32];
  __shared__ u16 Bs[128 * 32];
  const int tid = threadIdx.x;
  const int lane = tid & 63;
  const int wave = tid >> 6;
  const int wr = wave >> 1, wc = wave & 1;
  const int lr = lane & 15, kg = lane >> 4;
  const int rowbase = blockIdx.y * 128;
  const int colbase = blockIdx.x * 128;

  f32x4 acc[4][4];
#pragma unroll
  for (int m = 0; m < 4; m++)
#pragma unroll
    for (int n = 0; n < 4; n++) acc[m][n] = (f32x4){0.f, 0.f, 0.f, 0.f};

  const int r0 = tid >> 2, seg = tid & 3;
  long arow0 = -1, arow1 = -1;
  if (rowbase + r0 < M)      arow0 = GATHER ? gidx[rowbase + r0]      : (rowbase + r0);
  if (rowbase + r0 + 64 < M) arow1 = GATHER ? gidx[rowbase + r0 + 64] : (rowbase + r0 + 64);
  const u16* Brow0 = Bt + (size_t)(colbase + r0) * K + seg * 8;
  const u16* Brow1 = Bt + (size_t)(colbase + r0 + 64) * K + seg * 8;

  for (int k0 = 0; k0 < K; k0 += 32) {
    __syncthreads();
    uint4 a0 = {0, 0, 0, 0}, a1 = {0, 0, 0, 0};
    if (arow0 >= 0) a0 = *(const uint4*)(A + (size_t)arow0 * K + k0 + seg * 8);
    if (arow1 >= 0) a1 = *(const uint4*)(A + (size_t)arow1 * K + k0 + seg * 8);
    *(uint4*)(&As[r0 * 32 + seg * 8]) = a0;
    *(uint4*)(&As[(r0 + 64) * 32 + seg * 8]) = a1;
    *(uint4*)(&Bs[r0 * 32 + seg * 8]) = *(const uint4*)(Brow0 + k0);
    *(uint4*)(&Bs[(r0 + 64) * 32 + seg * 8]) = *(const uint4*)(Brow1 + k0);
    __syncthreads();
    bf16x8 af[4], bfr[4];
#pragma unroll
    for (int m = 0; m < 4; m++)
      af[m] = *(const bf16x8*)(&As[(wr * 64 + m * 16 + lr) * 32 + kg * 8]);
#pragma unroll
    for (int n = 0; n < 4; n++)
      bfr[n] = *(const bf16x8*)(&Bs[(wc * 64 + n * 16 + lr) * 32 + kg * 8]);
#pragma unroll
    for (int m = 0; m < 4; m++)
#pragma unroll
      for (int n = 0; n < 4; n++)
        acc[m][n] = __builtin_amdgcn_mfma_f32_16x16x32_bf16(af[m], bfr[n], acc[m][n], 0, 0, 0);
  }
  // epilogue: C/D layout col=lane&15, row=(lane>>4)*4+reg  [m89-verified]
#pragma unroll
  for (int n = 0; n < 4; n++) {
    int col = colbase + wc * 64 + n * 16 + lr;
    float bv = bias[col];
#pragma unroll
    for (int m = 0; m < 4; m++) {
      int row0 = rowbase + wr * 64 + m * 16 + kg * 4;
#pragma unroll
      for (int r = 0; r < 4; r++) {
        int row = row0 + r;
        if (row < M) {
          float v = acc[m][n][r] + bv;
          if (RELU) v = fmaxf(v, 0.f);
          C[(size_t)row * N + col] = f2bf(v);
        }
      }
    }
  }
}

__global__ __launch_bounds__(256) void gemm_bt_kernel(
    const u16* __restrict__ A, const u16* __restrict__ Bt,
    const float* __restrict__ bias, u16* __restrict__ C, int M, int N, int K) {
  gemm_core<false, false>(A, Bt, bias, C, M, N, K, nullptr);
}

__global__ __launch_bounds__(256) void moe_gemm1_kernel(
    const u16* __restrict__ x1b, const u16* __restrict__ W1t,
    const float* __restrict__ B1, u16* __restrict__ he,
    const int* __restrict__ cnt, const int* __restrict__ off,
    const int* __restrict__ idxlist) {
  int e = blockIdx.z;
  int M = cnt[e];
  if ((int)blockIdx.y * 128 >= M) return;
  gemm_core<true, true>(x1b, W1t + (size_t)e * DFF * DIMQ, B1 + e * DFF,
                        he + (size_t)off[e] * DFF, M, DFF, DIMQ, idxlist + off[e]);
}

__global__ __launch_bounds__(256) void moe_gemm2_kernel(
    const u16* __restrict__ he, const u16* __restrict__ W2t,
    const float* __restrict__ B2, u16* __restrict__ yslot,
    const int* __restrict__ cnt, const int* __restrict__ off) {
  int e = blockIdx.z;
  int M = cnt[e];
  if ((int)blockIdx.y * 128 >= M) return;
  gemm_core<false, false>(he + (size_t)off[e] * DFF, W2t + (size_t)e * DIMQ * DFF,
                          B2 + e * DIMQ, yslot + (size_t)off[e] * DIMQ, M, DIMQ, DFF, nullptr);
}

// ---------------- flash attention (vector fp32, per-thread q-row) ----------------
__global__ __launch_bounds__(256) void attn_kernel(
    const u16* __restrict__ qb, const u16* __restrict__ kb,
    const u16* __restrict__ vb, const int* __restrict__ amask,
    u16* __restrict__ hb) {
  __shared__ float Ks[32][64];
  __shared__ float Vs[32][64];
  __shared__ float mb[32];
  const int b = blockIdx.y >> 4;
  const int h = blockIdx.y & 15;
  const int qbase = blockIdx.x * 256;
  const int tq = qbase + threadIdx.x;

  float qv[64];
  {
    const u16* qp = qb + ((size_t)(b * TSEQ + tq)) * DIMQ + h * HD;
#pragma unroll
    for (int s8 = 0; s8 < 8; s8++) {
      uint4 u = *(const uint4*)(qp + s8 * 8);
      qv[s8 * 8 + 0] = bf_lo(u.x); qv[s8 * 8 + 1] = bf_hi(u.x);
      qv[s8 * 8 + 2] = bf_lo(u.y); qv[s8 * 8 + 3] = bf_hi(u.y);
      qv[s8 * 8 + 4] = bf_lo(u.z); qv[s8 * 8 + 5] = bf_hi(u.z);
      qv[s8 * 8 + 6] = bf_lo(u.w); qv[s8 * 8 + 7] = bf_hi(u.w);
    }
  }
  float ov[64];
#pragma unroll
  for (int d = 0; d < 64; d++) ov[d] = 0.f;
  float m_run = -3.0e38f, l_run = 0.f;

  const int srow = threadIdx.x >> 3, sseg = threadIdx.x & 7;
  const int ktiles = (qbase + 256) >> 5;
  for (int kt = 0; kt < ktiles; kt++) {
    const int k0 = kt * 32;
    __syncthreads();
    {
      const size_t g = ((size_t)(b * TSEQ + k0 + srow)) * DIMQ + h * HD + sseg * 8;
      uint4 u = *(const uint4*)(kb + g);
      Ks[srow][sseg * 8 + 0] = bf_lo(u.x); Ks[srow][sseg * 8 + 1] = bf_hi(u.x);
      Ks[srow][sseg * 8 + 2] = bf_lo(u.y); Ks[srow][sseg * 8 + 3] = bf_hi(u.y);
      Ks[srow][sseg * 8 + 4] = bf_lo(u.z); Ks[srow][sseg * 8 + 5] = bf_hi(u.z);
      Ks[srow][sseg * 8 + 6] = bf_lo(u.w); Ks[srow][sseg * 8 + 7] = bf_hi(u.w);
      uint4 w = *(const uint4*)(vb + g);
      Vs[srow][sseg * 8 + 0] = bf_lo(w.x); Vs[srow][sseg * 8 + 1] = bf_hi(w.x);
      Vs[srow][sseg * 8 + 2] = bf_lo(w.y); Vs[srow][sseg * 8 + 3] = bf_hi(w.y);
      Vs[srow][sseg * 8 + 4] = bf_lo(w.z); Vs[srow][sseg * 8 + 5] = bf_hi(w.z);
      Vs[srow][sseg * 8 + 6] = bf_lo(w.w); Vs[srow][sseg * 8 + 7] = bf_hi(w.w);
      if (threadIdx.x < 32)
        mb[threadIdx.x] = amask[b * TSEQ + k0 + threadIdx.x] ? 0.f : -1e9f;
    }
    __syncthreads();
    float s[32];
    float tmax = -3.0e38f;
#pragma unroll
    for (int j = 0; j < 32; j++) {
      float acc = 0.f;
      const float4* kr = (const float4*)(&Ks[j][0]);
#pragma unroll
      for (int d4 = 0; d4 < 16; d4++) {
        float4 kvv = kr[d4];
        acc += qv[d4 * 4 + 0] * kvv.x + qv[d4 * 4 + 1] * kvv.y +
               qv[d4 * 4 + 2] * kvv.z + qv[d4 * 4 + 3] * kvv.w;
      }
      float sv = acc * 0.125f + mb[j];
      if (k0 + j > tq) sv = -3.0e38f;
      s[j] = sv;
      tmax = fmaxf(tmax, sv);
    }
    float nm = fmaxf(m_run, tmax);
    float sc = __expf(m_run - nm);
    m_run = nm;
    l_run *= sc;
#pragma unroll
    for (int d = 0; d < 64; d++) ov[d] *= sc;
#pragma unroll
    for (int j = 0; j < 32; j++) {
      float p = __expf(s[j] - nm);
      l_run += p;
      const float4* vr = (const float4*)(&Vs[j][0]);
#pragma unroll
      for (int d4 = 0; d4 < 16; d4++) {
        float4 vv = vr[d4];
        ov[d4 * 4 + 0] += p * vv.x; ov[d4 * 4 + 1] += p * vv.y;
        ov[d4 * 4 + 2] += p * vv.z; ov[d4 * 4 + 3] += p * vv.w;
      }
    }
  }
  const float inv = 1.f / l_run;
  u16* op = hb + ((size_t)(b * TSEQ + tq)) * DIMQ + h * HD;
#pragma unroll
  for (int s8 = 0; s8 < 8; s8++) {
    uint4 u;
    u.x = (u32)f2bf(ov[s8 * 8 + 0] * inv) | ((u32)f2bf(ov[s8 * 8 + 1] * inv) << 16);
    u.y = (u32)f2bf(ov[s8 * 8 + 2] * inv) | ((u32)f2bf(ov[s8 * 8 + 3] * inv) << 16);
    u.z = (u32)f2bf(ov[s8 * 8 + 4] * inv) | ((u32)f2bf(ov[s8 * 8 + 5] * inv) << 16);
    u.w = (u32)f2bf(ov[s8 * 8 + 6] * inv) | ((u32)f2bf(ov[s8 * 8 + 7] * inv) << 16);
    *(uint4*)(op + s8 * 8) = u;
  }
}

// ---------------- add + layernorm (x + h) -> x1 f32 and x1b bf16 ----------------
__global__ __launch_bounds__(256) void addln_kernel(
    const float* __restrict__ xin, const u16* __restrict__ hres,
    const float* __restrict__ g, const float* __restrict__ beta,
    float* __restrict__ x1, u16* __restrict__ x1b) {
  __shared__ float red[8];
  int t = blockIdx.x;
  int d = threadIdx.x * 4;
  size_t base = (size_t)t * DIMQ + d;
  float4 xv = *(const float4*)(xin + base);
  uint2 hu = *(const uint2*)(hres + base);
  float v0 = xv.x + bf_lo(hu.x), v1 = xv.y + bf_hi(hu.x);
  float v2 = xv.z + bf_lo(hu.y), v3 = xv.w + bf_hi(hu.y);
  float s1 = v0 + v1 + v2 + v3;
  float s2 = v0 * v0 + v1 * v1 + v2 * v2 + v3 * v3;
#pragma unroll
  for (int off = 32; off; off >>= 1) {
    s1 += __shfl_down(s1, off);
    s2 += __shfl_down(s2, off);
  }
  int w = threadIdx.x >> 6;
  if ((threadIdx.x & 63) == 0) { red[w] = s1; red[4 + w] = s2; }
  __syncthreads();
  float S1 = red[0] + red[1] + red[2] + red[3];
  float S2 = red[4] + red[5] + red[6] + red[7];
  float m = S1 * (1.f / DIMQ);
  float var = S2 * (1.f / DIMQ) - m * m;
  float rs = rsqrtf(var + 1e-5f);
  float4 gv = *(const float4*)(g + d);
  float4 bv = *(const float4*)(beta + d);
  float o0 = (v0 - m) * rs * gv.x + bv.x;
  float o1 = (v1 - m) * rs * gv.y + bv.y;
  float o2 = (v2 - m) * rs * gv.z + bv.z;
  float o3 = (v3 - m) * rs * gv.w + bv.w;
  *(float4*)(x1 + base) = make_float4(o0, o1, o2, o3);
  uint2 pu;
  pu.x = (u32)f2bf(o0) | ((u32)f2bf(o1) << 16);
  pu.y = (u32)f2bf(o2) | ((u32)f2bf(o3) << 16);
  *(uint2*)(x1b + base) = pu;
}

// ---------------- router: logits, softmax, top-2, stats ----------------
__global__ __launch_bounds__(64) void router_kernel(
    const float* __restrict__ x1, const float* __restrict__ rw,
    const float* __restrict__ rb, int* __restrict__ topi,
    float* __restrict__ gkout, int* __restrict__ cnt, float* __restrict__ Psum) {
  int t = blockIdx.x;
  int l = threadIdx.x;
  float acc[8];
#pragma unroll
  for (int e = 0; e < 8; e++) acc[e] = 0.f;
  const float* xr = x1 + (size_t)t * DIMQ;
  for (int k = l; k < DIMQ; k += 64) {
    float xv = xr[k];
    const float* w = rw + (size_t)k * 8;
#pragma unroll
    for (int e = 0; e < 8; e++) acc[e] += xv * w[e];
  }
#pragma unroll
  for (int e = 0; e < 8; e++) {
#pragma unroll
    for (int off = 32; off; off >>= 1) acc[e] += __shfl_down(acc[e], off);
  }
  if (l == 0) {
    float lg[8], p[8];
    float mx = -3e38f;
#pragma unroll
    for (int e = 0; e < 8; e++) { lg[e] = acc[e] + rb[e]; mx = fmaxf(mx, lg[e]); }
    float sum = 0.f;
#pragma unroll
    for (int e = 0; e < 8; e++) { p[e] = expf(lg[e] - mx); sum += p[e]; }
    float isum = 1.f / sum;
#pragma unroll
    for (int e = 0; e < 8; e++) p[e] *= isum;
    int e0 = 0;
#pragma unroll
    for (int e = 1; e < 8; e++) if (p[e] > p[e0]) e0 = e;
    int e1 = (e0 == 0) ? 1 : 0;
#pragma unroll
    for (int e = 0; e < 8; e++) if (e != e0 && p[e] > p[e1]) e1 = e;
    float s2 = p[e0] + p[e1];
    topi[2 * t] = e0; topi[2 * t + 1] = e1;
    gkout[2 * t] = p[e0] / s2; gkout[2 * t + 1] = p[e1] / s2;
    atomicAdd(&cnt[e0], 1);
    atomicAdd(&cnt[e1], 1);
#pragma unroll
    for (int e = 0; e < 8; e++) atomicAdd(&Psum[e], p[e]);
  }
}

__global__ void offsets_kernel(const int* __restrict__ cnt, const float* __restrict__ Psum,
                               int* __restrict__ off, int* __restrict__ fill,
                               float* __restrict__ lb_out) {
  if (threadIdx.x == 0 && blockIdx.x == 0) {
    int o = 0;
    float lb = 0.f;
    for (int e = 0; e < NEXP; e++) {
      off[e] = o;
      fill[e] = o;
      o += cnt[e];
      lb += ((float)cnt[e] / (float)NTOK) * (Psum[e] / (float)NTOK);
    }
    lb_out[0] = (float)NEXP * lb;
  }
}

__global__ __launch_bounds__(256) void listbuild_kernel(
    const int* __restrict__ topi, int* fill, int* __restrict__ idxlist,
    int* __restrict__ posmap) {
  int t = blockIdx.x * 256 + threadIdx.x;
  if (t >= NTOK) return;
#pragma unroll
  for (int k = 0; k < 2; k++) {
    int e = topi[2 * t + k];
    int s = atomicAdd(&fill[e], 1);
    idxlist[s] = t;
    posmap[2 * t + k] = s;
  }
}

// ---------------- final: out = LN(x1 + g0*yslot[p0] + g1*yslot[p1]) ----------------
__global__ __launch_bounds__(256) void finalln_kernel(
    const float* __restrict__ x1, const u16* __restrict__ yslot,
    const int* __restrict__ posmap, const float* __restrict__ gkv,
    const float* __restrict__ g, const float* __restrict__ beta,
    float* __restrict__ out) {
  __shared__ float red[8];
  int t = blockIdx.x;
  int p0 = posmap[2 * t], p1 = posmap[2 * t + 1];
  float g0 = gkv[2 * t], g1 = gkv[2 * t + 1];
  int d = threadIdx.x * 4;
  size_t base = (size_t)t * DIMQ + d;
  float4 xv = *(const float4*)(x1 + base);
  uint2 y0 = *(const uint2*)(yslot + (size_t)p0 * DIMQ + d);
  uint2 y1 = *(const uint2*)(yslot + (size_t)p1 * DIMQ + d);
  float v0 = xv.x + g0 * bf_lo(y0.x) + g1 * bf_lo(y1.x);
  float v1 = xv.y + g0 * bf_hi(y0.x) + g1 * bf_hi(y1.x);
  float v2 = xv.z + g0 * bf_lo(y0.y) + g1 * bf_lo(y1.y);
  float v3 = xv.w + g0 * bf_hi(y0.y) + g1 * bf_hi(y1.y);
  float s1 = v0 + v1 + v2 + v3;
  float s2 = v0 * v0 + v1 * v1 + v2 * v2 + v3 * v3;
#pragma unroll
  for (int off = 32; off; off >>= 1) {
    s1 += __shfl_down(s1, off);
    s2 += __shfl_down(s2, off);
  }
  int w = threadIdx.x >> 6;
  if ((threadIdx.x & 63) == 0) { red[w] = s1; red[4 + w] = s2; }
  __syncthreads();
  float S1 = red[0] + red[1] + red[2] + red[3];
  float S2 = red[4] + red[5] + red[6] + red[7];
  float m = S1 * (1.f / DIMQ);
  float var = S2 * (1.f / DIMQ) - m * m;
  float rs = rsqrtf(var + 1e-5f);
  float4 gv = *(const float4*)(g + d);
  float4 bv = *(const float4*)(beta + d);
  float4 o;
  o.x = (v0 - m) * rs * gv.x + bv.x;
  o.y = (v1 - m) * rs * gv.y + bv.y;
  o.z = (v2 - m) * rs * gv.z + bv.z;
  o.w = (v3 - m) * rs * gv.w + bv.w;
  *(float4*)(out + base) = o;
}

// ---------------- host launch ----------------
extern "C" void kernel_launch(void* const* d_in, const int* in_sizes, int n_in,
                              void* d_out, int out_size, void* d_ws, size_t ws_size,
                              hipStream_t stream) {
  const float* x     = (const float*)d_in[0];
  const int*   amask = (const int*)d_in[1];
  const float* Wq    = (const float*)d_in[2];
  const float* bq    = (const float*)d_in[3];
  const float* Wk    = (const float*)d_in[4];
  const float* bk    = (const float*)d_in[5];
  const float* Wv    = (const float*)d_in[6];
  const float* bv    = (const float*)d_in[7];
  const float* Wo    = (const float*)d_in[8];
  const float* bo    = (const float*)d_in[9];
  const float* g1    = (const float*)d_in[10];
  const float* beta1 = (const float*)d_in[11];
  const float* rw    = (const float*)d_in[12];
  const float* rb    = (const float*)d_in[13];
  const float* W1    = (const float*)d_in[14];
  const float* B1    = (const float*)d_in[15];
  const float* W2    = (const float*)d_in[16];
  const float* B2    = (const float*)d_in[17];
  const float* g2    = (const float*)d_in[18];
  const float* beta2 = (const float*)d_in[19];
  float* out    = (float*)d_out;
  float* lb_out = out + (size_t)NTOK * DIMQ;

  char* ws = (char*)d_ws;
  size_t off_acc = 0;
  auto alloc = [&](size_t bytes) {
    void* p = ws + off_acc;
    off_acc += (bytes + 255) & ~(size_t)255;
    return p;
  };
  u16* xb    = (u16*)alloc((size_t)NTOK * DIMQ * 2);
  u16* qbuf  = (u16*)alloc((size_t)NTOK * DIMQ * 2);
  u16* kbuf  = (u16*)alloc((size_t)NTOK * DIMQ * 2);
  u16* vbuf  = (u16*)alloc((size_t)NTOK * DIMQ * 2);
  u16* hb    = (u16*)alloc((size_t)NTOK * DIMQ * 2);
  u16* ho    = (u16*)alloc((size_t)NTOK * DIMQ * 2);
  float* x1  = (float*)alloc((size_t)NTOK * DIMQ * 4);
  u16* x1b   = (u16*)alloc((size_t)NTOK * DIMQ * 2);
  u16* Wqt   = (u16*)alloc((size_t)DIMQ * DIMQ * 2);
  u16* Wkt   = (u16*)alloc((size_t)DIMQ * DIMQ * 2);
  u16* Wvt   = (u16*)alloc((size_t)DIMQ * DIMQ * 2);
  u16* Wot   = (u16*)alloc((size_t)DIMQ * DIMQ * 2);
  u16* W1t   = (u16*)alloc((size_t)NEXP * DFF * DIMQ * 2);
  u16* W2t   = (u16*)alloc((size_t)NEXP * DIMQ * DFF * 2);
  u16* he    = (u16*)alloc((size_t)2 * NTOK * DFF * 2);
  u16* yslot = (u16*)alloc((size_t)2 * NTOK * DIMQ * 2);
  char* stats = (char*)alloc(4096);
  int*   cnt   = (int*)stats;
  float* Psum  = (float*)(stats + 32);
  int*   offp  = (int*)(stats + 64);
  int*   fill  = (int*)(stats + 96);
  int* topi    = (int*)alloc((size_t)NTOK * 2 * 4);
  float* gkbuf = (float*)alloc((size_t)NTOK * 2 * 4);
  int* posmap  = (int*)alloc((size_t)NTOK * 2 * 4);
  int* idxlist = (int*)alloc((size_t)NTOK * 2 * 4);

  hipMemsetAsync(stats, 0, 64, stream);

  // converts / transposes
  cvt_f32_bf16<<<NTOK * DIMQ / 1024, 256, 0, stream>>>(x, xb, NTOK * DIMQ);
  transpose_f32_bf16<<<dim3(DIMQ / 32, DIMQ / 32, 1), 256, 0, stream>>>(Wq, Wqt, DIMQ, DIMQ);
  transpose_f32_bf16<<<dim3(DIMQ / 32, DIMQ / 32, 1), 256, 0, stream>>>(Wk, Wkt, DIMQ, DIMQ);
  transpose_f32_bf16<<<dim3(DIMQ / 32, DIMQ / 32, 1), 256, 0, stream>>>(Wv, Wvt, DIMQ, DIMQ);
  transpose_f32_bf16<<<dim3(DIMQ / 32, DIMQ / 32, 1), 256, 0, stream>>>(Wo, Wot, DIMQ, DIMQ);
  transpose_f32_bf16<<<dim3(DFF / 32, DIMQ / 32, NEXP), 256, 0, stream>>>(W1, W1t, DIMQ, DFF);
  transpose_f32_bf16<<<dim3(DIMQ / 32, DFF / 32, NEXP), 256, 0, stream>>>(W2, W2t, DFF, DIMQ);

  // attention path
  dim3 gproj(DIMQ / 128, NTOK / 128);
  gemm_bt_kernel<<<gproj, 256, 0, stream>>>(xb, Wqt, bq, qbuf, NTOK, DIMQ, DIMQ);
  gemm_bt_kernel<<<gproj, 256, 0, stream>>>(xb, Wkt, bk, kbuf, NTOK, DIMQ, DIMQ);
  gemm_bt_kernel<<<gproj, 256, 0, stream>>>(xb, Wvt, bv, vbuf, NTOK, DIMQ, DIMQ);
  attn_kernel<<<dim3(TSEQ / 256, BATCH * NHEADS), 256, 0, stream>>>(qbuf, kbuf, vbuf, amask, hb);
  gemm_bt_kernel<<<gproj, 256, 0, stream>>>(hb, Wot, bo, ho, NTOK, DIMQ, DIMQ);
  addln_kernel<<<NTOK, 256, 0, stream>>>(x, ho, g1, beta1, x1, x1b);

  // MoE path
  router_kernel<<<NTOK, 64, 0, stream>>>(x1, rw, rb, topi, gkbuf, cnt, Psum);
  offsets_kernel<<<1, 64, 0, stream>>>(cnt, Psum, offp, fill, lb_out);
  listbuild_kernel<<<NTOK / 256, 256, 0, stream>>>(topi, fill, idxlist, posmap);
  moe_gemm1_kernel<<<dim3(DFF / 128, NTOK / 128, NEXP), 256, 0, stream>>>(x1b, W1t, B1, he, cnt, offp, idxlist);
  moe_gemm2_kernel<<<dim3(DIMQ / 128, NTOK / 128, NEXP), 256, 0, stream>>>(he, W2t, B2, yslot, cnt, offp);
  finalln_kernel<<<NTOK, 256, 0, stream>>>(x1, yslot, posmap, gkbuf, g2, beta2, out);
}

// Round 2
// 2070.166 us; speedup vs baseline: 1.7469x; 1.7469x over previous
//
#include <hip/hip_runtime.h>
#include <hip/hip_bf16.h>
#include <stdint.h>

#define DIMQ   1024
#define NHEADS 16
#define HD     64
#define NEXP   8
#define DFF    4096
#define NTOK   8192
#define TSEQ   1024
#define BATCH  8

typedef unsigned short u16;
typedef unsigned int   u32;
typedef __attribute__((ext_vector_type(8))) short bf16x8;
typedef __attribute__((ext_vector_type(4))) float f32x4;

__device__ __forceinline__ float bf_lo(u32 w) { return __uint_as_float(w << 16); }
__device__ __forceinline__ float bf_hi(u32 w) { return __uint_as_float(w & 0xffff0000u); }
__device__ __forceinline__ u16 f2bf(float f) {
  u32 x = __float_as_uint(f);
  return (u16)((x + 0x7fffu + ((x >> 16) & 1u)) >> 16);
}

// ---------------- convert f32 -> bf16 ----------------
__global__ __launch_bounds__(256) void cvt_f32_bf16(const float* __restrict__ in,
                                                    u16* __restrict__ out, int n) {
  int i = (blockIdx.x * 256 + threadIdx.x) * 4;
  if (i >= n) return;
  float4 v = *(const float4*)(in + i);
  ushort4 o;
  o.x = f2bf(v.x); o.y = f2bf(v.y); o.z = f2bf(v.z); o.w = f2bf(v.w);
  *(ushort4*)(out + i) = o;
}

// ---------------- batched transpose f32[R][C] -> bf16[C][R] ----------------
__global__ __launch_bounds__(256) void transpose_f32_bf16(
    const float* __restrict__ in, u16* __restrict__ out, int R, int C) {
  __shared__ float tile[32][33];
  size_t base = (size_t)blockIdx.z * (size_t)R * (size_t)C;
  int tx = threadIdx.x & 31, ty = threadIdx.x >> 5;
  int c = blockIdx.x * 32 + tx;
#pragma unroll
  for (int i = 0; i < 4; i++) {
    int r = blockIdx.y * 32 + ty + i * 8;
    tile[ty + i * 8][tx] = in[base + (size_t)r * C + c];
  }
  __syncthreads();
  int rr = blockIdx.y * 32 + tx;
#pragma unroll
  for (int i = 0; i < 4; i++) {
    int cc = blockIdx.x * 32 + ty + i * 8;
    out[base + (size_t)cc * R + rr] = f2bf(tile[tx][ty + i * 8]);
  }
}

// ---------------- shared MFMA GEMM core: C[M,N] = A[M,K] * Bt[N,K]^T + bias ----------------
// 128x128 tile, BK=32, 256 threads (4 waves, 2x2), 4x4 fragments of 16x16x32 per wave.
// TRANSC: store C transposed as C[col*M + row] (used to produce V^T for attention).
template <bool GATHER, bool RELU, bool TRANSC>
__device__ __forceinline__ void gemm_core(
    const u16* __restrict__ A, const u16* __restrict__ Bt,
    const float* __restrict__ bias, u16* __restrict__ C,
    int M, int N, int K, const int* __restrict__ gidx) {
  __shared__ u16 As[128 * 32];
  __shared__ u16 Bs[128 * 32];
  const int tid = threadIdx.x;
  const int lane = tid & 63;
  const int wave = tid >> 6;
  const int wr = wave >> 1, wc = wave & 1;
  const int lr = lane & 15, kg = lane >> 4;
  const int rowbase = blockIdx.y * 128;
  const int colbase = blockIdx.x * 128;

  f32x4 acc[4][4];
#pragma unroll
  for (int m = 0; m < 4; m++)
#pragma unroll
    for (int n = 0; n < 4; n++) acc[m][n] = (f32x4){0.f, 0.f, 0.f, 0.f};

  const int r0 = tid >> 2, seg = tid & 3;
  long arow0 = -1, arow1 = -1;
  if (rowbase + r0 < M)      arow0 = GATHER ? gidx[rowbase + r0]      : (rowbase + r0);
  if (rowbase + r0 + 64 < M) arow1 = GATHER ? gidx[rowbase + r0 + 64] : (rowbase + r0 + 64);
  const u16* Brow0 = Bt + (size_t)(colbase + r0) * K + seg * 8;
  const u16* Brow1 = Bt + (size_t)(colbase + r0 + 64) * K + seg * 8;

  for (int k0 = 0; k0 < K; k0 += 32) {
    __syncthreads();
    uint4 a0 = {0, 0, 0, 0}, a1 = {0, 0, 0, 0};
    if (arow0 >= 0) a0 = *(const uint4*)(A + (size_t)arow0 * K + k0 + seg * 8);
    if (arow1 >= 0) a1 = *(const uint4*)(A + (size_t)arow1 * K + k0 + seg * 8);
    *(uint4*)(&As[r0 * 32 + seg * 8]) = a0;
    *(uint4*)(&As[(r0 + 64) * 32 + seg * 8]) = a1;
    *(uint4*)(&Bs[r0 * 32 + seg * 8]) = *(const uint4*)(Brow0 + k0);
    *(uint4*)(&Bs[(r0 + 64) * 32 + seg * 8]) = *(const uint4*)(Brow1 + k0);
    __syncthreads();
    bf16x8 af[4], bfr[4];
#pragma unroll
    for (int m = 0; m < 4; m++)
      af[m] = *(const bf16x8*)(&As[(wr * 64 + m * 16 + lr) * 32 + kg * 8]);
#pragma unroll
    for (int n = 0; n < 4; n++)
      bfr[n] = *(const bf16x8*)(&Bs[(wc * 64 + n * 16 + lr) * 32 + kg * 8]);
#pragma unroll
    for (int m = 0; m < 4; m++)
#pragma unroll
      for (int n = 0; n < 4; n++)
        acc[m][n] = __builtin_amdgcn_mfma_f32_16x16x32_bf16(af[m], bfr[n], acc[m][n], 0, 0, 0);
  }
  // epilogue: C/D layout col=lane&15, row=(lane>>4)*4+reg  [m89-verified]
#pragma unroll
  for (int n = 0; n < 4; n++) {
    int col = colbase + wc * 64 + n * 16 + lr;
    float bv = bias[col];
#pragma unroll
    for (int m = 0; m < 4; m++) {
      int row0 = rowbase + wr * 64 + m * 16 + kg * 4;
      if (TRANSC) {
        if (row0 + 3 < M) {
          ushort4 pk;
          pk.x = f2bf(acc[m][n][0] + bv);
          pk.y = f2bf(acc[m][n][1] + bv);
          pk.z = f2bf(acc[m][n][2] + bv);
          pk.w = f2bf(acc[m][n][3] + bv);
          *(ushort4*)(&C[(size_t)col * M + row0]) = pk;
        } else {
#pragma unroll
          for (int r = 0; r < 4; r++)
            if (row0 + r < M) C[(size_t)col * M + row0 + r] = f2bf(acc[m][n][r] + bv);
        }
      } else {
#pragma unroll
        for (int r = 0; r < 4; r++) {
          int row = row0 + r;
          if (row < M) {
            float v = acc[m][n][r] + bv;
            if (RELU) v = fmaxf(v, 0.f);
            C[(size_t)row * N + col] = f2bf(v);
          }
        }
      }
    }
  }
}

__global__ __launch_bounds__(256) void gemm_bt_kernel(
    const u16* __restrict__ A, const u16* __restrict__ Bt,
    const float* __restrict__ bias, u16* __restrict__ C, int M, int N, int K) {
  gemm_core<false, false, false>(A, Bt, bias, C, M, N, K, nullptr);
}

__global__ __launch_bounds__(256) void gemm_bt_tc_kernel(
    const u16* __restrict__ A, const u16* __restrict__ Bt,
    const float* __restrict__ bias, u16* __restrict__ C, int M, int N, int K) {
  gemm_core<false, false, true>(A, Bt, bias, C, M, N, K, nullptr);
}

__global__ __launch_bounds__(256) void moe_gemm1_kernel(
    const u16* __restrict__ x1b, const u16* __restrict__ W1t,
    const float* __restrict__ B1, u16* __restrict__ he,
    const int* __restrict__ cnt, const int* __restrict__ off,
    const int* __restrict__ idxlist) {
  int e = blockIdx.z;
  int M = cnt[e];
  if ((int)blockIdx.y * 128 >= M) return;
  gemm_core<true, true, false>(x1b, W1t + (size_t)e * DFF * DIMQ, B1 + e * DFF,
                               he + (size_t)off[e] * DFF, M, DFF, DIMQ, idxlist + off[e]);
}

__global__ __launch_bounds__(256) void moe_gemm2_kernel(
    const u16* __restrict__ he, const u16* __restrict__ W2t,
    const float* __restrict__ B2, u16* __restrict__ yslot,
    const int* __restrict__ cnt, const int* __restrict__ off) {
  int e = blockIdx.z;
  int M = cnt[e];
  if ((int)blockIdx.y * 128 >= M) return;
  gemm_core<false, false, false>(he + (size_t)off[e] * DFF, W2t + (size_t)e * DIMQ * DFF,
                                 B2 + e * DIMQ, yslot + (size_t)off[e] * DIMQ, M, DIMQ, DFF, nullptr);
}

// ---------------- MFMA flash attention ----------------
// Block = 256 threads = 4 waves; each wave owns 16 q-rows (block covers 64).
// Per 32-key tile: QK^T (4 MFMA), wave-parallel online softmax, PV (4 MFMA).
// K staged row-major [32key][64hd] with 16B-slot XOR swizzle (2-way-free reads).
// V staged from pre-transposed vbT [col][row] into LDS [64d][32key], swizzled.
__global__ __launch_bounds__(256) void attn_mfma_kernel(
    const u16* __restrict__ qb, const u16* __restrict__ kb,
    const u16* __restrict__ vbT, const int* __restrict__ amask,
    u16* __restrict__ hb) {
  __shared__ u16 Ks[32 * 64];      // [key][hd] rows of 128B, slot-swizzled
  __shared__ u16 VTs[64 * 32];     // [d][key] rows of 64B, slot-swizzled
  __shared__ u16 Ps[4][16 * 32];   // per-wave P tile [q][k], slot-swizzled
  __shared__ float mbias[32];

  const int b = blockIdx.y >> 4;
  const int h = blockIdx.y & 15;
  const int qb0 = blockIdx.x * 64;
  const int tid = threadIdx.x;
  const int lane = tid & 63;
  const int wq = tid >> 6;
  const int r16 = lane & 15;
  const int kg = lane >> 4;
  const int qrow0 = qb0 + wq * 16;

  // Q fragments (hoisted): lane holds Q[qrow0+r16][k0 + kg*8 + j], k0 in {0,32}
  bf16x8 qf[2];
  {
    const u16* qp = qb + ((size_t)(b * TSEQ + qrow0 + r16)) * DIMQ + h * HD + kg * 8;
    qf[0] = *(const bf16x8*)(qp);
    qf[1] = *(const bf16x8*)(qp + 32);
  }
  f32x4 acc[4];
#pragma unroll
  for (int db = 0; db < 4; db++) acc[db] = (f32x4){0.f, 0.f, 0.f, 0.f};
  float m_run[4], l_run[4];
#pragma unroll
  for (int i = 0; i < 4; i++) { m_run[i] = -3.0e38f; l_run[i] = 0.f; }

  // staging index precompute
  const int skey = tid >> 3, sslot = tid & 7;   // K: 32 keys x 8 slots(16B)
  const int sd = tid >> 2, sko = tid & 3;       // V: 64 d x 4 key-octets
  const u16* kgb = kb + (size_t)(b * TSEQ) * DIMQ + h * HD;
  const u16* vgb = vbT + (size_t)(h * HD) * NTOK + (size_t)b * TSEQ;

  const int nt = (qb0 + 64) >> 5;
  for (int kt = 0; kt < nt; kt++) {
    const int k0g = kt * 32;
    __syncthreads();
    {
      uint4 kv = *(const uint4*)(kgb + (size_t)(k0g + skey) * DIMQ + sslot * 8);
      *(uint4*)(&Ks[skey * 64 + ((sslot ^ (skey & 7)) * 8)]) = kv;
      uint4 vv = *(const uint4*)(vgb + (size_t)sd * NTOK + k0g + sko * 8);
      *(uint4*)(&VTs[sd * 32 + ((sko ^ (sd & 3)) * 8)]) = vv;
      if (tid < 32) mbias[tid] = amask[b * TSEQ + k0g + tid] ? 0.f : -1e9f;
    }
    __syncthreads();
    if (k0g < qrow0 + 16) {
      // ---- QK^T: D[q=kg*4+i][key] for two 16-key blocks ----
      f32x4 s0 = (f32x4){0.f, 0.f, 0.f, 0.f};
      f32x4 s1 = (f32x4){0.f, 0.f, 0.f, 0.f};
      {
        int key0 = r16;
        bf16x8 ka = *(const bf16x8*)(&Ks[key0 * 64 + ((kg ^ (key0 & 7)) * 8)]);
        bf16x8 kb2 = *(const bf16x8*)(&Ks[key0 * 64 + (((4 + kg) ^ (key0 & 7)) * 8)]);
        s0 = __builtin_amdgcn_mfma_f32_16x16x32_bf16(qf[0], ka, s0, 0, 0, 0);
        s0 = __builtin_amdgcn_mfma_f32_16x16x32_bf16(qf[1], kb2, s0, 0, 0, 0);
        int key1 = 16 + r16;
        bf16x8 kc = *(const bf16x8*)(&Ks[key1 * 64 + ((kg ^ (key1 & 7)) * 8)]);
        bf16x8 kd = *(const bf16x8*)(&Ks[key1 * 64 + (((4 + kg) ^ (key1 & 7)) * 8)]);
        s1 = __builtin_amdgcn_mfma_f32_16x16x32_bf16(qf[0], kc, s1, 0, 0, 0);
        s1 = __builtin_amdgcn_mfma_f32_16x16x32_bf16(qf[1], kd, s1, 0, 0, 0);
      }
      // ---- mask + online softmax (rows q = kg*4+i live across 16-lane group) ----
      float sv0[4], sv1[4], tm[4];
      float mb0 = mbias[r16], mb1 = mbias[16 + r16];
#pragma unroll
      for (int i = 0; i < 4; i++) {
        int qg = qrow0 + kg * 4 + i;
        float a = s0[i] * 0.125f + mb0;
        float c = s1[i] * 0.125f + mb1;
        if (k0g + r16 > qg)      a = -3.0e38f;
        if (k0g + 16 + r16 > qg) c = -3.0e38f;
        sv0[i] = a; sv1[i] = c;
        tm[i] = fmaxf(a, c);
      }
#pragma unroll
      for (int mk = 1; mk < 16; mk <<= 1) {
#pragma unroll
        for (int i = 0; i < 4; i++) tm[i] = fmaxf(tm[i], __shfl_xor(tm[i], mk));
      }
      float pr0[4], pr1[4];
#pragma unroll
      for (int i = 0; i < 4; i++) {
        float nm = fmaxf(m_run[i], tm[i]);
        float sc = __expf(m_run[i] - nm);
        m_run[i] = nm;
        pr0[i] = __expf(sv0[i] - nm);
        pr1[i] = __expf(sv1[i] - nm);
        l_run[i] = l_run[i] * sc + pr0[i] + pr1[i];
#pragma unroll
        for (int db = 0; db < 4; db++) acc[db][i] *= sc;
      }
      // ---- P -> LDS (bf16, slot-swizzled) ----
#pragma unroll
      for (int i = 0; i < 4; i++) {
        int qrl = kg * 4 + i;
        int sw = qrl & 3;
        Ps[wq][qrl * 32 + (((r16 >> 3) ^ sw) * 8) + (r16 & 7)] = f2bf(pr0[i]);
        Ps[wq][qrl * 32 + ((((16 + r16) >> 3) ^ sw) * 8) + (r16 & 7)] = f2bf(pr1[i]);
      }
      // ---- PV: A-frag = P[q=r16][kg*8+j], B-frag = V^T[d][keys] ----
      bf16x8 pf = *(const bf16x8*)(&Ps[wq][r16 * 32 + ((kg ^ (r16 & 3)) * 8)]);
#pragma unroll
      for (int db = 0; db < 4; db++) {
        int d = db * 16 + r16;
        bf16x8 vf = *(const bf16x8*)(&VTs[d * 32 + ((kg ^ (d & 3)) * 8)]);
        acc[db] = __builtin_amdgcn_mfma_f32_16x16x32_bf16(pf, vf, acc[db], 0, 0, 0);
      }
    }
  }
  // ---- epilogue: reduce l across 16-lane group, normalize, store ----
#pragma unroll
  for (int mk = 1; mk < 16; mk <<= 1) {
#pragma unroll
    for (int i = 0; i < 4; i++) l_run[i] += __shfl_xor(l_run[i], mk);
  }
#pragma unroll
  for (int i = 0; i < 4; i++) {
    float inv = 1.f / l_run[i];
    int qg = qrow0 + kg * 4 + i;
    u16* op = hb + ((size_t)(b * TSEQ + qg)) * DIMQ + h * HD + r16;
#pragma unroll
    for (int db = 0; db < 4; db++) op[db * 16] = f2bf(acc[db][i] * inv);
  }
}

// ---------------- add + layernorm (x + h) -> x1 f32 and x1b bf16 ----------------
__global__ __launch_bounds__(256) void addln_kernel(
    const float* __restrict__ xin, const u16* __restrict__ hres,
    const float* __restrict__ g, const float* __restrict__ beta,
    float* __restrict__ x1, u16* __restrict__ x1b) {
  __shared__ float red[8];
  int t = blockIdx.x;
  int d = threadIdx.x * 4;
  size_t base = (size_t)t * DIMQ + d;
  float4 xv = *(const float4*)(xin + base);
  uint2 hu = *(const uint2*)(hres + base);
  float v0 = xv.x + bf_lo(hu.x), v1 = xv.y + bf_hi(hu.x);
  float v2 = xv.z + bf_lo(hu.y), v3 = xv.w + bf_hi(hu.y);
  float s1 = v0 + v1 + v2 + v3;
  float s2 = v0 * v0 + v1 * v1 + v2 * v2 + v3 * v3;
#pragma unroll
  for (int off = 32; off; off >>= 1) {
    s1 += __shfl_down(s1, off);
    s2 += __shfl_down(s2, off);
  }
  int w = threadIdx.x >> 6;
  if ((threadIdx.x & 63) == 0) { red[w] = s1; red[4 + w] = s2; }
  __syncthreads();
  float S1 = red[0] + red[1] + red[2] + red[3];
  float S2 = red[4] + red[5] + red[6] + red[7];
  float m = S1 * (1.f / DIMQ);
  float var = S2 * (1.f / DIMQ) - m * m;
  float rs = rsqrtf(var + 1e-5f);
  float4 gv = *(const float4*)(g + d);
  float4 bv = *(const float4*)(beta + d);
  float o0 = (v0 - m) * rs * gv.x + bv.x;
  float o1 = (v1 - m) * rs * gv.y + bv.y;
  float o2 = (v2 - m) * rs * gv.z + bv.z;
  float o3 = (v3 - m) * rs * gv.w + bv.w;
  *(float4*)(x1 + base) = make_float4(o0, o1, o2, o3);
  uint2 pu;
  pu.x = (u32)f2bf(o0) | ((u32)f2bf(o1) << 16);
  pu.y = (u32)f2bf(o2) | ((u32)f2bf(o3) << 16);
  *(uint2*)(x1b + base) = pu;
}

// ---------------- router: logits, softmax, top-2, stats ----------------
__global__ __launch_bounds__(64) void router_kernel(
    const float* __restrict__ x1, const float* __restrict__ rw,
    const float* __restrict__ rb, int* __restrict__ topi,
    float* __restrict__ gkout, int* __restrict__ cnt, float* __restrict__ Psum) {
  int t = blockIdx.x;
  int l = threadIdx.x;
  float acc[8];
#pragma unroll
  for (int e = 0; e < 8; e++) acc[e] = 0.f;
  const float* xr = x1 + (size_t)t * DIMQ;
  for (int k = l; k < DIMQ; k += 64) {
    float xv = xr[k];
    const float* w = rw + (size_t)k * 8;
#pragma unroll
    for (int e = 0; e < 8; e++) acc[e] += xv * w[e];
  }
#pragma unroll
  for (int e = 0; e < 8; e++) {
#pragma unroll
    for (int off = 32; off; off >>= 1) acc[e] += __shfl_down(acc[e], off);
  }
  if (l == 0) {
    float lg[8], p[8];
    float mx = -3e38f;
#pragma unroll
    for (int e = 0; e < 8; e++) { lg[e] = acc[e] + rb[e]; mx = fmaxf(mx, lg[e]); }
    float sum = 0.f;
#pragma unroll
    for (int e = 0; e < 8; e++) { p[e] = expf(lg[e] - mx); sum += p[e]; }
    float isum = 1.f / sum;
#pragma unroll
    for (int e = 0; e < 8; e++) p[e] *= isum;
    int e0 = 0;
#pragma unroll
    for (int e = 1; e < 8; e++) if (p[e] > p[e0]) e0 = e;
    int e1 = (e0 == 0) ? 1 : 0;
#pragma unroll
    for (int e = 0; e < 8; e++) if (e != e0 && p[e] > p[e1]) e1 = e;
    float s2 = p[e0] + p[e1];
    topi[2 * t] = e0; topi[2 * t + 1] = e1;
    gkout[2 * t] = p[e0] / s2; gkout[2 * t + 1] = p[e1] / s2;
    atomicAdd(&cnt[e0], 1);
    atomicAdd(&cnt[e1], 1);
#pragma unroll
    for (int e = 0; e < 8; e++) atomicAdd(&Psum[e], p[e]);
  }
}

__global__ void offsets_kernel(const int* __restrict__ cnt, const float* __restrict__ Psum,
                               int* __restrict__ off, int* __restrict__ fill,
                               float* __restrict__ lb_out) {
  if (threadIdx.x == 0 && blockIdx.x == 0) {
    int o = 0;
    float lb = 0.f;
    for (int e = 0; e < NEXP; e++) {
      off[e] = o;
      fill[e] = o;
      o += cnt[e];
      lb += ((float)cnt[e] / (float)NTOK) * (Psum[e] / (float)NTOK);
    }
    lb_out[0] = (float)NEXP * lb;
  }
}

__global__ __launch_bounds__(256) void listbuild_kernel(
    const int* __restrict__ topi, int* fill, int* __restrict__ idxlist,
    int* __restrict__ posmap) {
  int t = blockIdx.x * 256 + threadIdx.x;
  if (t >= NTOK) return;
#pragma unroll
  for (int k = 0; k < 2; k++) {
    int e = topi[2 * t + k];
    int s = atomicAdd(&fill[e], 1);
    idxlist[s] = t;
    posmap[2 * t + k] = s;
  }
}

// ---------------- final: out = LN(x1 + g0*yslot[p0] + g1*yslot[p1]) ----------------
__global__ __launch_bounds__(256) void finalln_kernel(
    const float* __restrict__ x1, const u16* __restrict__ yslot,
    const int* __restrict__ posmap, const float* __restrict__ gkv,
    const float* __restrict__ g, const float* __restrict__ beta,
    float* __restrict__ out) {
  __shared__ float red[8];
  int t = blockIdx.x;
  int p0 = posmap[2 * t], p1 = posmap[2 * t + 1];
  float g0 = gkv[2 * t], g1 = gkv[2 * t + 1];
  int d = threadIdx.x * 4;
  size_t base = (size_t)t * DIMQ + d;
  float4 xv = *(const float4*)(x1 + base);
  uint2 y0 = *(const uint2*)(yslot + (size_t)p0 * DIMQ + d);
  uint2 y1 = *(const uint2*)(yslot + (size_t)p1 * DIMQ + d);
  float v0 = xv.x + g0 * bf_lo(y0.x) + g1 * bf_lo(y1.x);
  float v1 = xv.y + g0 * bf_hi(y0.x) + g1 * bf_hi(y1.x);
  float v2 = xv.z + g0 * bf_lo(y0.y) + g1 * bf_lo(y1.y);
  float v3 = xv.w + g0 * bf_hi(y0.y) + g1 * bf_hi(y1.y);
  float s1 = v0 + v1 + v2 + v3;
  float s2 = v0 * v0 + v1 * v1 + v2 * v2 + v3 * v3;
#pragma unroll
  for (int off = 32; off; off >>= 1) {
    s1 += __shfl_down(s1, off);
    s2 += __shfl_down(s2, off);
  }
  int w = threadIdx.x >> 6;
  if ((threadIdx.x & 63) == 0) { red[w] = s1; red[4 + w] = s2; }
  __syncthreads();
  float S1 = red[0] + red[1] + red[2] + red[3];
  float S2 = red[4] + red[5] + red[6] + red[7];
  float m = S1 * (1.f / DIMQ);
  float var = S2 * (1.f / DIMQ) - m * m;
  float rs = rsqrtf(var + 1e-5f);
  float4 gv = *(const float4*)(g + d);
  float4 bv = *(const float4*)(beta + d);
  float4 o;
  o.x = (v0 - m) * rs * gv.x + bv.x;
  o.y = (v1 - m) * rs * gv.y + bv.y;
  o.z = (v2 - m) * rs * gv.z + bv.z;
  o.w = (v3 - m) * rs * gv.w + bv.w;
  *(float4*)(out + base) = o;
}

// ---------------- host launch ----------------
extern "C" void kernel_launch(void* const* d_in, const int* in_sizes, int n_in,
                              void* d_out, int out_size, void* d_ws, size_t ws_size,
                              hipStream_t stream) {
  const float* x     = (const float*)d_in[0];
  const int*   amask = (const int*)d_in[1];
  const float* Wq    = (const float*)d_in[2];
  const float* bq    = (const float*)d_in[3];
  const float* Wk    = (const float*)d_in[4];
  const float* bk    = (const float*)d_in[5];
  const float* Wv    = (const float*)d_in[6];
  const float* bv    = (const float*)d_in[7];
  const float* Wo    = (const float*)d_in[8];
  const float* bo    = (const float*)d_in[9];
  const float* g1    = (const float*)d_in[10];
  const float* beta1 = (const float*)d_in[11];
  const float* rw    = (const float*)d_in[12];
  const float* rb    = (const float*)d_in[13];
  const float* W1    = (const float*)d_in[14];
  const float* B1    = (const float*)d_in[15];
  const float* W2    = (const float*)d_in[16];
  const float* B2    = (const float*)d_in[17];
  const float* g2    = (const float*)d_in[18];
  const float* beta2 = (const float*)d_in[19];
  float* out    = (float*)d_out;
  float* lb_out = out + (size_t)NTOK * DIMQ;

  char* ws = (char*)d_ws;
  size_t off_acc = 0;
  auto alloc = [&](size_t bytes) {
    void* p = ws + off_acc;
    off_acc += (bytes + 255) & ~(size_t)255;
    return p;
  };
  u16* xb    = (u16*)alloc((size_t)NTOK * DIMQ * 2);
  u16* qbuf  = (u16*)alloc((size_t)NTOK * DIMQ * 2);
  u16* kbuf  = (u16*)alloc((size_t)NTOK * DIMQ * 2);
  u16* vbufT = (u16*)alloc((size_t)NTOK * DIMQ * 2);  // transposed: [col][row]
  u16* hb    = (u16*)alloc((size_t)NTOK * DIMQ * 2);
  u16* ho    = (u16*)alloc((size_t)NTOK * DIMQ * 2);
  float* x1  = (float*)alloc((size_t)NTOK * DIMQ * 4);
  u16* x1b   = (u16*)alloc((size_t)NTOK * DIMQ * 2);
  u16* Wqt   = (u16*)alloc((size_t)DIMQ * DIMQ * 2);
  u16* Wkt   = (u16*)alloc((size_t)DIMQ * DIMQ * 2);
  u16* Wvt   = (u16*)alloc((size_t)DIMQ * DIMQ * 2);
  u16* Wot   = (u16*)alloc((size_t)DIMQ * DIMQ * 2);
  u16* W1t   = (u16*)alloc((size_t)NEXP * DFF * DIMQ * 2);
  u16* W2t   = (u16*)alloc((size_t)NEXP * DIMQ * DFF * 2);
  u16* he    = (u16*)alloc((size_t)2 * NTOK * DFF * 2);
  u16* yslot = (u16*)alloc((size_t)2 * NTOK * DIMQ * 2);
  char* stats = (char*)alloc(4096);
  int*   cnt   = (int*)stats;
  float* Psum  = (float*)(stats + 32);
  int*   offp  = (int*)(stats + 64);
  int*   fill  = (int*)(stats + 96);
  int* topi    = (int*)alloc((size_t)NTOK * 2 * 4);
  float* gkbuf = (float*)alloc((size_t)NTOK * 2 * 4);
  int* posmap  = (int*)alloc((size_t)NTOK * 2 * 4);
  int* idxlist = (int*)alloc((size_t)NTOK * 2 * 4);

  hipMemsetAsync(stats, 0, 64, stream);

  // converts / transposes
  cvt_f32_bf16<<<NTOK * DIMQ / 1024, 256, 0, stream>>>(x, xb, NTOK * DIMQ);
  transpose_f32_bf16<<<dim3(DIMQ / 32, DIMQ / 32, 1), 256, 0, stream>>>(Wq, Wqt, DIMQ, DIMQ);
  transpose_f32_bf16<<<dim3(DIMQ / 32, DIMQ / 32, 1), 256, 0, stream>>>(Wk, Wkt, DIMQ, DIMQ);
  transpose_f32_bf16<<<dim3(DIMQ / 32, DIMQ / 32, 1), 256, 0, stream>>>(Wv, Wvt, DIMQ, DIMQ);
  transpose_f32_bf16<<<dim3(DIMQ / 32, DIMQ / 32, 1), 256, 0, stream>>>(Wo, Wot, DIMQ, DIMQ);
  transpose_f32_bf16<<<dim3(DFF / 32, DIMQ / 32, NEXP), 256, 0, stream>>>(W1, W1t, DIMQ, DFF);
  transpose_f32_bf16<<<dim3(DIMQ / 32, DFF / 32, NEXP), 256, 0, stream>>>(W2, W2t, DFF, DIMQ);

  // attention path
  dim3 gproj(DIMQ / 128, NTOK / 128);
  gemm_bt_kernel<<<gproj, 256, 0, stream>>>(xb, Wqt, bq, qbuf, NTOK, DIMQ, DIMQ);
  gemm_bt_kernel<<<gproj, 256, 0, stream>>>(xb, Wkt, bk, kbuf, NTOK, DIMQ, DIMQ);
  gemm_bt_tc_kernel<<<gproj, 256, 0, stream>>>(xb, Wvt, bv, vbufT, NTOK, DIMQ, DIMQ);
  attn_mfma_kernel<<<dim3(TSEQ / 64, BATCH * NHEADS), 256, 0, stream>>>(qbuf, kbuf, vbufT, amask, hb);
  gemm_bt_kernel<<<gproj, 256, 0, stream>>>(hb, Wot, bo, ho, NTOK, DIMQ, DIMQ);
  addln_kernel<<<NTOK, 256, 0, stream>>>(x, ho, g1, beta1, x1, x1b);

  // MoE path
  router_kernel<<<NTOK, 64, 0, stream>>>(x1, rw, rb, topi, gkbuf, cnt, Psum);
  offsets_kernel<<<1, 64, 0, stream>>>(cnt, Psum, offp, fill, lb_out);
  listbuild_kernel<<<NTOK / 256, 256, 0, stream>>>(topi, fill, idxlist, posmap);
  moe_gemm1_kernel<<<dim3(DFF / 128, NTOK / 128, NEXP), 256, 0, stream>>>(x1b, W1t, B1, he, cnt, offp, idxlist);
  moe_gemm2_kernel<<<dim3(DIMQ / 128, NTOK / 128, NEXP), 256, 0, stream>>>(he, W2t, B2, yslot, cnt, offp);
  finalln_kernel<<<NTOK, 256, 0, stream>>>(x1, yslot, posmap, gkbuf, g2, beta2, out);
}

// Round 3
// 989.613 us; speedup vs baseline: 3.6544x; 2.0919x over previous
//
#include <hip/hip_runtime.h>
#include <hip/hip_bf16.h>
#include <stdint.h>

#define DIMQ   1024
#define NHEADS 16
#define HD     64
#define NEXP   8
#define DFF    4096
#define NTOK   8192
#define TSEQ   1024
#define BATCH  8

typedef unsigned short u16;
typedef unsigned int   u32;
typedef __attribute__((ext_vector_type(8))) short bf16x8;
typedef __attribute__((ext_vector_type(4))) float f32x4;

__device__ __forceinline__ float bf_lo(u32 w) { return __uint_as_float(w << 16); }
__device__ __forceinline__ float bf_hi(u32 w) { return __uint_as_float(w & 0xffff0000u); }
__device__ __forceinline__ u16 f2bf(float f) {
  u32 x = __float_as_uint(f);
  return (u16)((x + 0x7fffu + ((x >> 16) & 1u)) >> 16);
}

// ---------------- convert f32 -> bf16 ----------------
__global__ __launch_bounds__(256) void cvt_f32_bf16(const float* __restrict__ in,
                                                    u16* __restrict__ out, int n) {
  int i = (blockIdx.x * 256 + threadIdx.x) * 4;
  if (i >= n) return;
  float4 v = *(const float4*)(in + i);
  ushort4 o;
  o.x = f2bf(v.x); o.y = f2bf(v.y); o.z = f2bf(v.z); o.w = f2bf(v.w);
  *(ushort4*)(out + i) = o;
}

// ---------------- batched transpose f32[R][C] -> bf16[C][R] ----------------
__global__ __launch_bounds__(256) void transpose_f32_bf16(
    const float* __restrict__ in, u16* __restrict__ out, int R, int C) {
  __shared__ float tile[32][33];
  size_t base = (size_t)blockIdx.z * (size_t)R * (size_t)C;
  int tx = threadIdx.x & 31, ty = threadIdx.x >> 5;
  int c = blockIdx.x * 32 + tx;
#pragma unroll
  for (int i = 0; i < 4; i++) {
    int r = blockIdx.y * 32 + ty + i * 8;
    tile[ty + i * 8][tx] = in[base + (size_t)r * C + c];
  }
  __syncthreads();
  int rr = blockIdx.y * 32 + tx;
#pragma unroll
  for (int i = 0; i < 4; i++) {
    int cc = blockIdx.x * 32 + ty + i * 8;
    out[base + (size_t)cc * R + rr] = f2bf(tile[tx][ty + i * 8]);
  }
}

// ---------------- shared MFMA GEMM core: C[M,N] = A[M,K] * Bt[N,K]^T + bias ----------------
// 128x128 tile, BK=32, 256 threads (4 waves, 2x2), 4x4 fragments of 16x16x32 per wave.
// TRANSC: store C transposed as C[col*M + row] (used to produce V^T for attention).
template <bool GATHER, bool RELU, bool TRANSC>
__device__ __forceinline__ void gemm_core(
    const u16* __restrict__ A, const u16* __restrict__ Bt,
    const float* __restrict__ bias, u16* __restrict__ C,
    int M, int N, int K, const int* __restrict__ gidx) {
  __shared__ u16 As[128 * 32];
  __shared__ u16 Bs[128 * 32];
  const int tid = threadIdx.x;
  const int lane = tid & 63;
  const int wave = tid >> 6;
  const int wr = wave >> 1, wc = wave & 1;
  const int lr = lane & 15, kg = lane >> 4;
  const int rowbase = blockIdx.y * 128;
  const int colbase = blockIdx.x * 128;

  f32x4 acc[4][4];
#pragma unroll
  for (int m = 0; m < 4; m++)
#pragma unroll
    for (int n = 0; n < 4; n++) acc[m][n] = (f32x4){0.f, 0.f, 0.f, 0.f};

  const int r0 = tid >> 2, seg = tid & 3;
  long arow0 = -1, arow1 = -1;
  if (rowbase + r0 < M)      arow0 = GATHER ? gidx[rowbase + r0]      : (rowbase + r0);
  if (rowbase + r0 + 64 < M) arow1 = GATHER ? gidx[rowbase + r0 + 64] : (rowbase + r0 + 64);
  const u16* Brow0 = Bt + (size_t)(colbase + r0) * K + seg * 8;
  const u16* Brow1 = Bt + (size_t)(colbase + r0 + 64) * K + seg * 8;

  for (int k0 = 0; k0 < K; k0 += 32) {
    __syncthreads();
    uint4 a0 = {0, 0, 0, 0}, a1 = {0, 0, 0, 0};
    if (arow0 >= 0) a0 = *(const uint4*)(A + (size_t)arow0 * K + k0 + seg * 8);
    if (arow1 >= 0) a1 = *(const uint4*)(A + (size_t)arow1 * K + k0 + seg * 8);
    *(uint4*)(&As[r0 * 32 + seg * 8]) = a0;
    *(uint4*)(&As[(r0 + 64) * 32 + seg * 8]) = a1;
    *(uint4*)(&Bs[r0 * 32 + seg * 8]) = *(const uint4*)(Brow0 + k0);
    *(uint4*)(&Bs[(r0 + 64) * 32 + seg * 8]) = *(const uint4*)(Brow1 + k0);
    __syncthreads();
    bf16x8 af[4], bfr[4];
#pragma unroll
    for (int m = 0; m < 4; m++)
      af[m] = *(const bf16x8*)(&As[(wr * 64 + m * 16 + lr) * 32 + kg * 8]);
#pragma unroll
    for (int n = 0; n < 4; n++)
      bfr[n] = *(const bf16x8*)(&Bs[(wc * 64 + n * 16 + lr) * 32 + kg * 8]);
#pragma unroll
    for (int m = 0; m < 4; m++)
#pragma unroll
      for (int n = 0; n < 4; n++)
        acc[m][n] = __builtin_amdgcn_mfma_f32_16x16x32_bf16(af[m], bfr[n], acc[m][n], 0, 0, 0);
  }
  // epilogue: C/D layout col=lane&15, row=(lane>>4)*4+reg  [m89-verified]
#pragma unroll
  for (int n = 0; n < 4; n++) {
    int col = colbase + wc * 64 + n * 16 + lr;
    float bv = bias[col];
#pragma unroll
    for (int m = 0; m < 4; m++) {
      int row0 = rowbase + wr * 64 + m * 16 + kg * 4;
      if (TRANSC) {
        if (row0 + 3 < M) {
          ushort4 pk;
          pk.x = f2bf(acc[m][n][0] + bv);
          pk.y = f2bf(acc[m][n][1] + bv);
          pk.z = f2bf(acc[m][n][2] + bv);
          pk.w = f2bf(acc[m][n][3] + bv);
          *(ushort4*)(&C[(size_t)col * M + row0]) = pk;
        } else {
#pragma unroll
          for (int r = 0; r < 4; r++)
            if (row0 + r < M) C[(size_t)col * M + row0 + r] = f2bf(acc[m][n][r] + bv);
        }
      } else {
#pragma unroll
        for (int r = 0; r < 4; r++) {
          int row = row0 + r;
          if (row < M) {
            float v = acc[m][n][r] + bv;
            if (RELU) v = fmaxf(v, 0.f);
            C[(size_t)row * N + col] = f2bf(v);
          }
        }
      }
    }
  }
}

__global__ __launch_bounds__(256) void gemm_bt_kernel(
    const u16* __restrict__ A, const u16* __restrict__ Bt,
    const float* __restrict__ bias, u16* __restrict__ C, int M, int N, int K) {
  gemm_core<false, false, false>(A, Bt, bias, C, M, N, K, nullptr);
}

__global__ __launch_bounds__(256) void gemm_bt_tc_kernel(
    const u16* __restrict__ A, const u16* __restrict__ Bt,
    const float* __restrict__ bias, u16* __restrict__ C, int M, int N, int K) {
  gemm_core<false, false, true>(A, Bt, bias, C, M, N, K, nullptr);
}

__global__ __launch_bounds__(256) void moe_gemm1_kernel(
    const u16* __restrict__ x1b, const u16* __restrict__ W1t,
    const float* __restrict__ B1, u16* __restrict__ he,
    const int* __restrict__ cnt, const int* __restrict__ off,
    const int* __restrict__ idxlist) {
  int e = blockIdx.z;
  int M = cnt[e];
  if ((int)blockIdx.y * 128 >= M) return;
  gemm_core<true, true, false>(x1b, W1t + (size_t)e * DFF * DIMQ, B1 + e * DFF,
                               he + (size_t)off[e] * DFF, M, DFF, DIMQ, idxlist + off[e]);
}

__global__ __launch_bounds__(256) void moe_gemm2_kernel(
    const u16* __restrict__ he, const u16* __restrict__ W2t,
    const float* __restrict__ B2, u16* __restrict__ yslot,
    const int* __restrict__ cnt, const int* __restrict__ off) {
  int e = blockIdx.z;
  int M = cnt[e];
  if ((int)blockIdx.y * 128 >= M) return;
  gemm_core<false, false, false>(he + (size_t)off[e] * DFF, W2t + (size_t)e * DIMQ * DFF,
                                 B2 + e * DIMQ, yslot + (size_t)off[e] * DIMQ, M, DIMQ, DFF, nullptr);
}

// ---------------- MFMA flash attention ----------------
__global__ __launch_bounds__(256) void attn_mfma_kernel(
    const u16* __restrict__ qb, const u16* __restrict__ kb,
    const u16* __restrict__ vbT, const int* __restrict__ amask,
    u16* __restrict__ hb) {
  __shared__ u16 Ks[32 * 64];
  __shared__ u16 VTs[64 * 32];
  __shared__ u16 Ps[4][16 * 32];
  __shared__ float mbias[32];

  const int b = blockIdx.y >> 4;
  const int h = blockIdx.y & 15;
  const int qb0 = blockIdx.x * 64;
  const int tid = threadIdx.x;
  const int lane = tid & 63;
  const int wq = tid >> 6;
  const int r16 = lane & 15;
  const int kg = lane >> 4;
  const int qrow0 = qb0 + wq * 16;

  bf16x8 qf[2];
  {
    const u16* qp = qb + ((size_t)(b * TSEQ + qrow0 + r16)) * DIMQ + h * HD + kg * 8;
    qf[0] = *(const bf16x8*)(qp);
    qf[1] = *(const bf16x8*)(qp + 32);
  }
  f32x4 acc[4];
#pragma unroll
  for (int db = 0; db < 4; db++) acc[db] = (f32x4){0.f, 0.f, 0.f, 0.f};
  float m_run[4], l_run[4];
#pragma unroll
  for (int i = 0; i < 4; i++) { m_run[i] = -3.0e38f; l_run[i] = 0.f; }

  const int skey = tid >> 3, sslot = tid & 7;
  const int sd = tid >> 2, sko = tid & 3;
  const u16* kgb = kb + (size_t)(b * TSEQ) * DIMQ + h * HD;
  const u16* vgb = vbT + (size_t)(h * HD) * NTOK + (size_t)b * TSEQ;

  const int nt = (qb0 + 64) >> 5;
  for (int kt = 0; kt < nt; kt++) {
    const int k0g = kt * 32;
    __syncthreads();
    {
      uint4 kv = *(const uint4*)(kgb + (size_t)(k0g + skey) * DIMQ + sslot * 8);
      *(uint4*)(&Ks[skey * 64 + ((sslot ^ (skey & 7)) * 8)]) = kv;
      uint4 vv = *(const uint4*)(vgb + (size_t)sd * NTOK + k0g + sko * 8);
      *(uint4*)(&VTs[sd * 32 + ((sko ^ (sd & 3)) * 8)]) = vv;
      if (tid < 32) mbias[tid] = amask[b * TSEQ + k0g + tid] ? 0.f : -1e9f;
    }
    __syncthreads();
    if (k0g < qrow0 + 16) {
      f32x4 s0 = (f32x4){0.f, 0.f, 0.f, 0.f};
      f32x4 s1 = (f32x4){0.f, 0.f, 0.f, 0.f};
      {
        int key0 = r16;
        bf16x8 ka = *(const bf16x8*)(&Ks[key0 * 64 + ((kg ^ (key0 & 7)) * 8)]);
        bf16x8 kb2 = *(const bf16x8*)(&Ks[key0 * 64 + (((4 + kg) ^ (key0 & 7)) * 8)]);
        s0 = __builtin_amdgcn_mfma_f32_16x16x32_bf16(qf[0], ka, s0, 0, 0, 0);
        s0 = __builtin_amdgcn_mfma_f32_16x16x32_bf16(qf[1], kb2, s0, 0, 0, 0);
        int key1 = 16 + r16;
        bf16x8 kc = *(const bf16x8*)(&Ks[key1 * 64 + ((kg ^ (key1 & 7)) * 8)]);
        bf16x8 kd = *(const bf16x8*)(&Ks[key1 * 64 + (((4 + kg) ^ (key1 & 7)) * 8)]);
        s1 = __builtin_amdgcn_mfma_f32_16x16x32_bf16(qf[0], kc, s1, 0, 0, 0);
        s1 = __builtin_amdgcn_mfma_f32_16x16x32_bf16(qf[1], kd, s1, 0, 0, 0);
      }
      float sv0[4], sv1[4], tm[4];
      float mb0 = mbias[r16], mb1 = mbias[16 + r16];
#pragma unroll
      for (int i = 0; i < 4; i++) {
        int qg = qrow0 + kg * 4 + i;
        float a = s0[i] * 0.125f + mb0;
        float c = s1[i] * 0.125f + mb1;
        if (k0g + r16 > qg)      a = -3.0e38f;
        if (k0g + 16 + r16 > qg) c = -3.0e38f;
        sv0[i] = a; sv1[i] = c;
        tm[i] = fmaxf(a, c);
      }
#pragma unroll
      for (int mk = 1; mk < 16; mk <<= 1) {
#pragma unroll
        for (int i = 0; i < 4; i++) tm[i] = fmaxf(tm[i], __shfl_xor(tm[i], mk));
      }
      float pr0[4], pr1[4];
#pragma unroll
      for (int i = 0; i < 4; i++) {
        float nm = fmaxf(m_run[i], tm[i]);
        float sc = __expf(m_run[i] - nm);
        m_run[i] = nm;
        pr0[i] = __expf(sv0[i] - nm);
        pr1[i] = __expf(sv1[i] - nm);
        l_run[i] = l_run[i] * sc + pr0[i] + pr1[i];
#pragma unroll
        for (int db = 0; db < 4; db++) acc[db][i] *= sc;
      }
#pragma unroll
      for (int i = 0; i < 4; i++) {
        int qrl = kg * 4 + i;
        int sw = qrl & 3;
        Ps[wq][qrl * 32 + (((r16 >> 3) ^ sw) * 8) + (r16 & 7)] = f2bf(pr0[i]);
        Ps[wq][qrl * 32 + ((((16 + r16) >> 3) ^ sw) * 8) + (r16 & 7)] = f2bf(pr1[i]);
      }
      bf16x8 pf = *(const bf16x8*)(&Ps[wq][r16 * 32 + ((kg ^ (r16 & 3)) * 8)]);
#pragma unroll
      for (int db = 0; db < 4; db++) {
        int d = db * 16 + r16;
        bf16x8 vf = *(const bf16x8*)(&VTs[d * 32 + ((kg ^ (d & 3)) * 8)]);
        acc[db] = __builtin_amdgcn_mfma_f32_16x16x32_bf16(pf, vf, acc[db], 0, 0, 0);
      }
    }
  }
#pragma unroll
  for (int mk = 1; mk < 16; mk <<= 1) {
#pragma unroll
    for (int i = 0; i < 4; i++) l_run[i] += __shfl_xor(l_run[i], mk);
  }
#pragma unroll
  for (int i = 0; i < 4; i++) {
    float inv = 1.f / l_run[i];
    int qg = qrow0 + kg * 4 + i;
    u16* op = hb + ((size_t)(b * TSEQ + qg)) * DIMQ + h * HD + r16;
#pragma unroll
    for (int db = 0; db < 4; db++) op[db * 16] = f2bf(acc[db][i] * inv);
  }
}

// ---------------- add + layernorm (x + h) -> x1 f32 and x1b bf16 ----------------
__global__ __launch_bounds__(256) void addln_kernel(
    const float* __restrict__ xin, const u16* __restrict__ hres,
    const float* __restrict__ g, const float* __restrict__ beta,
    float* __restrict__ x1, u16* __restrict__ x1b) {
  __shared__ float red[8];
  int t = blockIdx.x;
  int d = threadIdx.x * 4;
  size_t base = (size_t)t * DIMQ + d;
  float4 xv = *(const float4*)(xin + base);
  uint2 hu = *(const uint2*)(hres + base);
  float v0 = xv.x + bf_lo(hu.x), v1 = xv.y + bf_hi(hu.x);
  float v2 = xv.z + bf_lo(hu.y), v3 = xv.w + bf_hi(hu.y);
  float s1 = v0 + v1 + v2 + v3;
  float s2 = v0 * v0 + v1 * v1 + v2 * v2 + v3 * v3;
#pragma unroll
  for (int off = 32; off; off >>= 1) {
    s1 += __shfl_down(s1, off);
    s2 += __shfl_down(s2, off);
  }
  int w = threadIdx.x >> 6;
  if ((threadIdx.x & 63) == 0) { red[w] = s1; red[4 + w] = s2; }
  __syncthreads();
  float S1 = red[0] + red[1] + red[2] + red[3];
  float S2 = red[4] + red[5] + red[6] + red[7];
  float m = S1 * (1.f / DIMQ);
  float var = S2 * (1.f / DIMQ) - m * m;
  float rs = rsqrtf(var + 1e-5f);
  float4 gv = *(const float4*)(g + d);
  float4 bv = *(const float4*)(beta + d);
  float o0 = (v0 - m) * rs * gv.x + bv.x;
  float o1 = (v1 - m) * rs * gv.y + bv.y;
  float o2 = (v2 - m) * rs * gv.z + bv.z;
  float o3 = (v3 - m) * rs * gv.w + bv.w;
  *(float4*)(x1 + base) = make_float4(o0, o1, o2, o3);
  uint2 pu;
  pu.x = (u32)f2bf(o0) | ((u32)f2bf(o1) << 16);
  pu.y = (u32)f2bf(o2) | ((u32)f2bf(o3) << 16);
  *(uint2*)(x1b + base) = pu;
}

// ---------------- router: logits, softmax, top-2 (NO global atomics) ----------------
// 4 waves/block, each wave owns one token. Outputs topi, renormalized gates, probs.
__global__ __launch_bounds__(256) void router_kernel(
    const float* __restrict__ x1, const float* __restrict__ rw,
    const float* __restrict__ rb, int* __restrict__ topi,
    float* __restrict__ gkout, float* __restrict__ probs) {
  int t = blockIdx.x * 4 + (threadIdx.x >> 6);
  int l = threadIdx.x & 63;
  float acc[8];
#pragma unroll
  for (int e = 0; e < 8; e++) acc[e] = 0.f;
  const float* xr = x1 + (size_t)t * DIMQ;
  for (int k = l; k < DIMQ; k += 64) {
    float xv = xr[k];
    const float* w = rw + (size_t)k * 8;
#pragma unroll
    for (int e = 0; e < 8; e++) acc[e] += xv * w[e];
  }
#pragma unroll
  for (int e = 0; e < 8; e++) {
#pragma unroll
    for (int off = 32; off; off >>= 1) acc[e] += __shfl_down(acc[e], off);
  }
  if (l == 0) {
    float lg[8], p[8];
    float mx = -3e38f;
#pragma unroll
    for (int e = 0; e < 8; e++) { lg[e] = acc[e] + rb[e]; mx = fmaxf(mx, lg[e]); }
    float sum = 0.f;
#pragma unroll
    for (int e = 0; e < 8; e++) { p[e] = expf(lg[e] - mx); sum += p[e]; }
    float isum = 1.f / sum;
#pragma unroll
    for (int e = 0; e < 8; e++) p[e] *= isum;
    int e0 = 0;
#pragma unroll
    for (int e = 1; e < 8; e++) if (p[e] > p[e0]) e0 = e;
    int e1 = (e0 == 0) ? 1 : 0;
#pragma unroll
    for (int e = 0; e < 8; e++) if (e != e0 && p[e] > p[e1]) e1 = e;
    float s2 = p[e0] + p[e1];
    topi[2 * t] = e0; topi[2 * t + 1] = e1;
    gkout[2 * t] = p[e0] / s2; gkout[2 * t + 1] = p[e1] / s2;
    float* pp = probs + (size_t)t * 8;
#pragma unroll
    for (int e = 0; e < 8; e++) pp[e] = p[e];
  }
}

// ---------------- stats: cnt[e], Psum[e] with block-aggregated atomics ----------------
__global__ __launch_bounds__(256) void stats_kernel(
    const float* __restrict__ probs, const int* __restrict__ topi,
    int* __restrict__ cnt, float* __restrict__ Psum) {
  __shared__ float sps[4][8];
  __shared__ int   slc[4][8];
  float ps[8];
  int lc[8];
#pragma unroll
  for (int e = 0; e < 8; e++) { ps[e] = 0.f; lc[e] = 0; }
  int t = blockIdx.x * 256 + threadIdx.x;   // grid sized to cover NTOK exactly
  {
    const float* p = probs + (size_t)t * 8;
#pragma unroll
    for (int e = 0; e < 8; e++) ps[e] += p[e];
    lc[topi[2 * t]]++;
    lc[topi[2 * t + 1]]++;
  }
#pragma unroll
  for (int e = 0; e < 8; e++) {
#pragma unroll
    for (int off = 32; off; off >>= 1) {
      ps[e] += __shfl_down(ps[e], off);
      lc[e] += __shfl_down(lc[e], off);
    }
  }
  int w = threadIdx.x >> 6;
  if ((threadIdx.x & 63) == 0) {
#pragma unroll
    for (int e = 0; e < 8; e++) { sps[w][e] = ps[e]; slc[w][e] = lc[e]; }
  }
  __syncthreads();
  if (threadIdx.x < 8) {
    float fp = sps[0][threadIdx.x] + sps[1][threadIdx.x] + sps[2][threadIdx.x] + sps[3][threadIdx.x];
    int   fc = slc[0][threadIdx.x] + slc[1][threadIdx.x] + slc[2][threadIdx.x] + slc[3][threadIdx.x];
    atomicAdd(&Psum[threadIdx.x], fp);
    atomicAdd(&cnt[threadIdx.x], fc);
  }
}

__global__ void offsets_kernel(const int* __restrict__ cnt, const float* __restrict__ Psum,
                               int* __restrict__ off, int* __restrict__ fill,
                               float* __restrict__ lb_out) {
  if (threadIdx.x == 0 && blockIdx.x == 0) {
    int o = 0;
    float lb = 0.f;
    for (int e = 0; e < NEXP; e++) {
      off[e] = o;
      fill[e] = o;
      o += cnt[e];
      lb += ((float)cnt[e] / (float)NTOK) * (Psum[e] / (float)NTOK);
    }
    lb_out[0] = (float)NEXP * lb;
  }
}

// ---------------- listbuild: block-aggregated slot assignment ----------------
__global__ __launch_bounds__(256) void listbuild_kernel(
    const int* __restrict__ topi, int* fill, int* __restrict__ idxlist,
    int* __restrict__ posmap) {
  __shared__ int bcnt[8];
  __shared__ int base[8];
  __shared__ int bofs[8];
  int t = blockIdx.x * 256 + threadIdx.x;
  if (threadIdx.x < 8) { bcnt[threadIdx.x] = 0; bofs[threadIdx.x] = 0; }
  __syncthreads();
  int e0 = topi[2 * t], e1 = topi[2 * t + 1];
  atomicAdd(&bcnt[e0], 1);
  atomicAdd(&bcnt[e1], 1);
  __syncthreads();
  if (threadIdx.x < 8) base[threadIdx.x] = atomicAdd(&fill[threadIdx.x], bcnt[threadIdx.x]);
  __syncthreads();
  int s0 = base[e0] + atomicAdd(&bofs[e0], 1);
  idxlist[s0] = t;
  posmap[2 * t] = s0;
  int s1 = base[e1] + atomicAdd(&bofs[e1], 1);
  idxlist[s1] = t;
  posmap[2 * t + 1] = s1;
}

// ---------------- final: out = LN(x1 + g0*yslot[p0] + g1*yslot[p1]) ----------------
__global__ __launch_bounds__(256) void finalln_kernel(
    const float* __restrict__ x1, const u16* __restrict__ yslot,
    const int* __restrict__ posmap, const float* __restrict__ gkv,
    const float* __restrict__ g, const float* __restrict__ beta,
    float* __restrict__ out) {
  __shared__ float red[8];
  int t = blockIdx.x;
  int p0 = posmap[2 * t], p1 = posmap[2 * t + 1];
  float g0 = gkv[2 * t], g1 = gkv[2 * t + 1];
  int d = threadIdx.x * 4;
  size_t base = (size_t)t * DIMQ + d;
  float4 xv = *(const float4*)(x1 + base);
  uint2 y0 = *(const uint2*)(yslot + (size_t)p0 * DIMQ + d);
  uint2 y1 = *(const uint2*)(yslot + (size_t)p1 * DIMQ + d);
  float v0 = xv.x + g0 * bf_lo(y0.x) + g1 * bf_lo(y1.x);
  float v1 = xv.y + g0 * bf_hi(y0.x) + g1 * bf_hi(y1.x);
  float v2 = xv.z + g0 * bf_lo(y0.y) + g1 * bf_lo(y1.y);
  float v3 = xv.w + g0 * bf_hi(y0.y) + g1 * bf_hi(y1.y);
  float s1 = v0 + v1 + v2 + v3;
  float s2 = v0 * v0 + v1 * v1 + v2 * v2 + v3 * v3;
#pragma unroll
  for (int off = 32; off; off >>= 1) {
    s1 += __shfl_down(s1, off);
    s2 += __shfl_down(s2, off);
  }
  int w = threadIdx.x >> 6;
  if ((threadIdx.x & 63) == 0) { red[w] = s1; red[4 + w] = s2; }
  __syncthreads();
  float S1 = red[0] + red[1] + red[2] + red[3];
  float S2 = red[4] + red[5] + red[6] + red[7];
  float m = S1 * (1.f / DIMQ);
  float var = S2 * (1.f / DIMQ) - m * m;
  float rs = rsqrtf(var + 1e-5f);
  float4 gv = *(const float4*)(g + d);
  float4 bv = *(const float4*)(beta + d);
  float4 o;
  o.x = (v0 - m) * rs * gv.x + bv.x;
  o.y = (v1 - m) * rs * gv.y + bv.y;
  o.z = (v2 - m) * rs * gv.z + bv.z;
  o.w = (v3 - m) * rs * gv.w + bv.w;
  *(float4*)(out + base) = o;
}

// ---------------- host launch ----------------
extern "C" void kernel_launch(void* const* d_in, const int* in_sizes, int n_in,
                              void* d_out, int out_size, void* d_ws, size_t ws_size,
                              hipStream_t stream) {
  const float* x     = (const float*)d_in[0];
  const int*   amask = (const int*)d_in[1];
  const float* Wq    = (const float*)d_in[2];
  const float* bq    = (const float*)d_in[3];
  const float* Wk    = (const float*)d_in[4];
  const float* bk    = (const float*)d_in[5];
  const float* Wv    = (const float*)d_in[6];
  const float* bv    = (const float*)d_in[7];
  const float* Wo    = (const float*)d_in[8];
  const float* bo    = (const float*)d_in[9];
  const float* g1    = (const float*)d_in[10];
  const float* beta1 = (const float*)d_in[11];
  const float* rw    = (const float*)d_in[12];
  const float* rb    = (const float*)d_in[13];
  const float* W1    = (const float*)d_in[14];
  const float* B1    = (const float*)d_in[15];
  const float* W2    = (const float*)d_in[16];
  const float* B2    = (const float*)d_in[17];
  const float* g2    = (const float*)d_in[18];
  const float* beta2 = (const float*)d_in[19];
  float* out    = (float*)d_out;
  float* lb_out = out + (size_t)NTOK * DIMQ;

  char* ws = (char*)d_ws;
  size_t off_acc = 0;
  auto alloc = [&](size_t bytes) {
    void* p = ws + off_acc;
    off_acc += (bytes + 255) & ~(size_t)255;
    return p;
  };
  u16* xb    = (u16*)alloc((size_t)NTOK * DIMQ * 2);
  u16* qbuf  = (u16*)alloc((size_t)NTOK * DIMQ * 2);
  u16* kbuf  = (u16*)alloc((size_t)NTOK * DIMQ * 2);
  u16* vbufT = (u16*)alloc((size_t)NTOK * DIMQ * 2);  // transposed: [col][row]
  u16* hb    = (u16*)alloc((size_t)NTOK * DIMQ * 2);
  u16* ho    = (u16*)alloc((size_t)NTOK * DIMQ * 2);
  float* x1  = (float*)alloc((size_t)NTOK * DIMQ * 4);
  u16* x1b   = (u16*)alloc((size_t)NTOK * DIMQ * 2);
  u16* Wqt   = (u16*)alloc((size_t)DIMQ * DIMQ * 2);
  u16* Wkt   = (u16*)alloc((size_t)DIMQ * DIMQ * 2);
  u16* Wvt   = (u16*)alloc((size_t)DIMQ * DIMQ * 2);
  u16* Wot   = (u16*)alloc((size_t)DIMQ * DIMQ * 2);
  u16* W1t   = (u16*)alloc((size_t)NEXP * DFF * DIMQ * 2);
  u16* W2t   = (u16*)alloc((size_t)NEXP * DIMQ * DFF * 2);
  u16* he    = (u16*)alloc((size_t)2 * NTOK * DFF * 2);
  u16* yslot = (u16*)alloc((size_t)2 * NTOK * DIMQ * 2);
  char* stats = (char*)alloc(4096);
  int*   cnt   = (int*)stats;
  float* Psum  = (float*)(stats + 32);
  int*   offp  = (int*)(stats + 64);
  int*   fill  = (int*)(stats + 96);
  int* topi    = (int*)alloc((size_t)NTOK * 2 * 4);
  float* gkbuf = (float*)alloc((size_t)NTOK * 2 * 4);
  int* posmap  = (int*)alloc((size_t)NTOK * 2 * 4);
  int* idxlist = (int*)alloc((size_t)NTOK * 2 * 4);
  float* probs = (float*)alloc((size_t)NTOK * 8 * 4);

  hipMemsetAsync(stats, 0, 64, stream);

  // converts / transposes
  cvt_f32_bf16<<<NTOK * DIMQ / 1024, 256, 0, stream>>>(x, xb, NTOK * DIMQ);
  transpose_f32_bf16<<<dim3(DIMQ / 32, DIMQ / 32, 1), 256, 0, stream>>>(Wq, Wqt, DIMQ, DIMQ);
  transpose_f32_bf16<<<dim3(DIMQ / 32, DIMQ / 32, 1), 256, 0, stream>>>(Wk, Wkt, DIMQ, DIMQ);
  transpose_f32_bf16<<<dim3(DIMQ / 32, DIMQ / 32, 1), 256, 0, stream>>>(Wv, Wvt, DIMQ, DIMQ);
  transpose_f32_bf16<<<dim3(DIMQ / 32, DIMQ / 32, 1), 256, 0, stream>>>(Wo, Wot, DIMQ, DIMQ);
  transpose_f32_bf16<<<dim3(DFF / 32, DIMQ / 32, NEXP), 256, 0, stream>>>(W1, W1t, DIMQ, DFF);
  transpose_f32_bf16<<<dim3(DIMQ / 32, DFF / 32, NEXP), 256, 0, stream>>>(W2, W2t, DFF, DIMQ);

  // attention path
  dim3 gproj(DIMQ / 128, NTOK / 128);
  gemm_bt_kernel<<<gproj, 256, 0, stream>>>(xb, Wqt, bq, qbuf, NTOK, DIMQ, DIMQ);
  gemm_bt_kernel<<<gproj, 256, 0, stream>>>(xb, Wkt, bk, kbuf, NTOK, DIMQ, DIMQ);
  gemm_bt_tc_kernel<<<gproj, 256, 0, stream>>>(xb, Wvt, bv, vbufT, NTOK, DIMQ, DIMQ);
  attn_mfma_kernel<<<dim3(TSEQ / 64, BATCH * NHEADS), 256, 0, stream>>>(qbuf, kbuf, vbufT, amask, hb);
  gemm_bt_kernel<<<gproj, 256, 0, stream>>>(hb, Wot, bo, ho, NTOK, DIMQ, DIMQ);
  addln_kernel<<<NTOK, 256, 0, stream>>>(x, ho, g1, beta1, x1, x1b);

  // MoE path
  router_kernel<<<NTOK / 4, 256, 0, stream>>>(x1, rw, rb, topi, gkbuf, probs);
  stats_kernel<<<NTOK / 256, 256, 0, stream>>>(probs, topi, cnt, Psum);
  offsets_kernel<<<1, 64, 0, stream>>>(cnt, Psum, offp, fill, lb_out);
  listbuild_kernel<<<NTOK / 256, 256, 0, stream>>>(topi, fill, idxlist, posmap);
  moe_gemm1_kernel<<<dim3(DFF / 128, NTOK / 128, NEXP), 256, 0, stream>>>(x1b, W1t, B1, he, cnt, offp, idxlist);
  moe_gemm2_kernel<<<dim3(DIMQ / 128, NTOK / 128, NEXP), 256, 0, stream>>>(he, W2t, B2, yslot, cnt, offp);
  finalln_kernel<<<NTOK, 256, 0, stream>>>(x1, yslot, posmap, gkbuf, g2, beta2, out);
}

// Round 4
// 934.443 us; speedup vs baseline: 3.8701x; 1.0590x over previous
//
#include <hip/hip_runtime.h>
#include <hip/hip_bf16.h>
#include <stdint.h>

#define DIMQ   1024
#define NHEADS 16
#define HD     64
#define NEXP   8
#define DFF    4096
#define NTOK   8192
#define TSEQ   1024
#define BATCH  8

typedef unsigned short u16;
typedef unsigned int   u32;
typedef __attribute__((ext_vector_type(8))) short bf16x8;
typedef __attribute__((ext_vector_type(4))) float f32x4;

__device__ __forceinline__ float bf_lo(u32 w) { return __uint_as_float(w << 16); }
__device__ __forceinline__ float bf_hi(u32 w) { return __uint_as_float(w & 0xffff0000u); }
__device__ __forceinline__ u16 f2bf(float f) {
  u32 x = __float_as_uint(f);
  return (u16)((x + 0x7fffu + ((x >> 16) & 1u)) >> 16);
}

// async 16B global -> LDS (linear dest: wave base + lane*16)
__device__ __forceinline__ void gload16(const u16* g, u16* l) {
  __builtin_amdgcn_global_load_lds((const __attribute__((address_space(1))) u32*)g,
                                   (__attribute__((address_space(3))) u32*)l, 16, 0, 0);
}

// ---------------- convert f32 -> bf16 ----------------
__global__ __launch_bounds__(256) void cvt_f32_bf16(const float* __restrict__ in,
                                                    u16* __restrict__ out, int n) {
  int i = (blockIdx.x * 256 + threadIdx.x) * 4;
  if (i >= n) return;
  float4 v = *(const float4*)(in + i);
  ushort4 o;
  o.x = f2bf(v.x); o.y = f2bf(v.y); o.z = f2bf(v.z); o.w = f2bf(v.w);
  *(ushort4*)(out + i) = o;
}

// ---------------- batched transpose f32[R][C] -> bf16[C][R] ----------------
__global__ __launch_bounds__(256) void transpose_f32_bf16(
    const float* __restrict__ in, u16* __restrict__ out, int R, int C) {
  __shared__ float tile[32][33];
  size_t base = (size_t)blockIdx.z * (size_t)R * (size_t)C;
  int tx = threadIdx.x & 31, ty = threadIdx.x >> 5;
  int c = blockIdx.x * 32 + tx;
#pragma unroll
  for (int i = 0; i < 4; i++) {
    int r = blockIdx.y * 32 + ty + i * 8;
    tile[ty + i * 8][tx] = in[base + (size_t)r * C + c];
  }
  __syncthreads();
  int rr = blockIdx.y * 32 + tx;
#pragma unroll
  for (int i = 0; i < 4; i++) {
    int cc = blockIdx.x * 32 + ty + i * 8;
    out[base + (size_t)cc * R + rr] = f2bf(tile[tx][ty + i * 8]);
  }
}

// ---------------- shared MFMA GEMM core: C[M,N] = A[M,K] * Bt[N,K]^T + bias ----------------
// 128x128 tile, BK=32, 256 threads (4 waves, 2x2), 4x4 fragments of 16x16x32 per wave.
// Staging: global_load_lds width=16, linear LDS dest, inverse-swizzled global source:
//   physical 16B slot s holds logical k-slot s ^ ((row>>1)&3)  -> conflict-free ds_read_b128.
// TRANSC: store C transposed as C[col*M + row] (used to produce V^T for attention).
template <bool GATHER, bool RELU, bool TRANSC>
__device__ __forceinline__ void gemm_core(
    const u16* __restrict__ A, const u16* __restrict__ Bt,
    const float* __restrict__ bias, u16* __restrict__ C,
    int M, int N, int K, const int* __restrict__ gidx) {
  __shared__ u16 As[128 * 32];
  __shared__ u16 Bs[128 * 32];
  const int tid = threadIdx.x;
  const int lane = tid & 63;
  const int wave = tid >> 6;
  const int wr = wave >> 1, wc = wave & 1;
  const int lr = lane & 15, kg = lane >> 4;
  const int rowbase = blockIdx.y * 128;
  const int colbase = blockIdx.x * 128;

  f32x4 acc[4][4];
#pragma unroll
  for (int m = 0; m < 4; m++)
#pragma unroll
    for (int n = 0; n < 4; n++) acc[m][n] = (f32x4){0.f, 0.f, 0.f, 0.f};

  // staging: thread tid <-> (row r0 = tid>>2, phys slot seg = tid&3); logical slot = seg ^ ((r0>>1)&3)
  const int r0 = tid >> 2, seg = tid & 3;
  const int slog = seg ^ ((r0 >> 1) & 3);
  int ar0 = rowbase + r0;      if (ar0 >= M) ar0 = M - 1;   // clamp; masked at epilogue
  int ar1 = rowbase + r0 + 64; if (ar1 >= M) ar1 = M - 1;
  const long arow0 = GATHER ? gidx[ar0] : ar0;
  const long arow1 = GATHER ? gidx[ar1] : ar1;
  const u16* Aptr0 = A + (size_t)arow0 * K + slog * 8;
  const u16* Aptr1 = A + (size_t)arow1 * K + slog * 8;
  const u16* Bptr0 = Bt + (size_t)(colbase + r0) * K + slog * 8;
  const u16* Bptr1 = Bt + (size_t)(colbase + r0 + 64) * K + slog * 8;
  u16* ldsA0 = &As[tid * 8];
  u16* ldsA1 = &As[2048 + tid * 8];
  u16* ldsB0 = &Bs[tid * 8];
  u16* ldsB1 = &Bs[2048 + tid * 8];

  const int swz = (lr >> 1) & 3;  // read-side swizzle for fragment rows (row = *+lr)

  for (int k0 = 0; k0 < K; k0 += 32) {
    gload16(Aptr0 + k0, ldsA0);
    gload16(Aptr1 + k0, ldsA1);
    gload16(Bptr0 + k0, ldsB0);
    gload16(Bptr1 + k0, ldsB1);
    __syncthreads();   // drains vmcnt(0): staged data visible
    bf16x8 af[4], bfr[4];
#pragma unroll
    for (int m = 0; m < 4; m++)
      af[m] = *(const bf16x8*)(&As[(wr * 64 + m * 16 + lr) * 32 + ((kg ^ swz) * 8)]);
#pragma unroll
    for (int n = 0; n < 4; n++)
      bfr[n] = *(const bf16x8*)(&Bs[(wc * 64 + n * 16 + lr) * 32 + ((kg ^ swz) * 8)]);
#pragma unroll
    for (int m = 0; m < 4; m++)
#pragma unroll
      for (int n = 0; n < 4; n++)
        acc[m][n] = __builtin_amdgcn_mfma_f32_16x16x32_bf16(af[m], bfr[n], acc[m][n], 0, 0, 0);
    __syncthreads();   // LDS consumed; safe to overwrite next iter
  }
  // epilogue: C/D layout col=lane&15, row=(lane>>4)*4+reg  [m89-verified]
#pragma unroll
  for (int n = 0; n < 4; n++) {
    int col = colbase + wc * 64 + n * 16 + lr;
    float bv = bias[col];
#pragma unroll
    for (int m = 0; m < 4; m++) {
      int row0 = rowbase + wr * 64 + m * 16 + kg * 4;
      if (TRANSC) {
        if (row0 + 3 < M) {
          ushort4 pk;
          pk.x = f2bf(acc[m][n][0] + bv);
          pk.y = f2bf(acc[m][n][1] + bv);
          pk.z = f2bf(acc[m][n][2] + bv);
          pk.w = f2bf(acc[m][n][3] + bv);
          *(ushort4*)(&C[(size_t)col * M + row0]) = pk;
        } else {
#pragma unroll
          for (int r = 0; r < 4; r++)
            if (row0 + r < M) C[(size_t)col * M + row0 + r] = f2bf(acc[m][n][r] + bv);
        }
      } else {
#pragma unroll
        for (int r = 0; r < 4; r++) {
          int row = row0 + r;
          if (row < M) {
            float v = acc[m][n][r] + bv;
            if (RELU) v = fmaxf(v, 0.f);
            C[(size_t)row * N + col] = f2bf(v);
          }
        }
      }
    }
  }
}

__global__ __launch_bounds__(256) void gemm_bt_kernel(
    const u16* __restrict__ A, const u16* __restrict__ Bt,
    const float* __restrict__ bias, u16* __restrict__ C, int M, int N, int K) {
  gemm_core<false, false, false>(A, Bt, bias, C, M, N, K, nullptr);
}

__global__ __launch_bounds__(256) void gemm_bt_tc_kernel(
    const u16* __restrict__ A, const u16* __restrict__ Bt,
    const float* __restrict__ bias, u16* __restrict__ C, int M, int N, int K) {
  gemm_core<false, false, true>(A, Bt, bias, C, M, N, K, nullptr);
}

__global__ __launch_bounds__(256) void moe_gemm1_kernel(
    const u16* __restrict__ x1b, const u16* __restrict__ W1t,
    const float* __restrict__ B1, u16* __restrict__ he,
    const int* __restrict__ cnt, const int* __restrict__ off,
    const int* __restrict__ idxlist) {
  int e = blockIdx.z;
  int M = cnt[e];
  if ((int)blockIdx.y * 128 >= M) return;
  gemm_core<true, true, false>(x1b, W1t + (size_t)e * DFF * DIMQ, B1 + e * DFF,
                               he + (size_t)off[e] * DFF, M, DFF, DIMQ, idxlist + off[e]);
}

__global__ __launch_bounds__(256) void moe_gemm2_kernel(
    const u16* __restrict__ he, const u16* __restrict__ W2t,
    const float* __restrict__ B2, u16* __restrict__ yslot,
    const int* __restrict__ cnt, const int* __restrict__ off) {
  int e = blockIdx.z;
  int M = cnt[e];
  if ((int)blockIdx.y * 128 >= M) return;
  gemm_core<false, false, false>(he + (size_t)off[e] * DFF, W2t + (size_t)e * DIMQ * DFF,
                                 B2 + e * DIMQ, yslot + (size_t)off[e] * DIMQ, M, DIMQ, DFF, nullptr);
}

// ---------------- MFMA flash attention ----------------
__global__ __launch_bounds__(256) void attn_mfma_kernel(
    const u16* __restrict__ qb, const u16* __restrict__ kb,
    const u16* __restrict__ vbT, const int* __restrict__ amask,
    u16* __restrict__ hb) {
  __shared__ u16 Ks[32 * 64];
  __shared__ u16 VTs[64 * 32];
  __shared__ u16 Ps[4][16 * 32];
  __shared__ float mbias[32];

  const int b = blockIdx.y >> 4;
  const int h = blockIdx.y & 15;
  const int qb0 = blockIdx.x * 64;
  const int tid = threadIdx.x;
  const int lane = tid & 63;
  const int wq = tid >> 6;
  const int r16 = lane & 15;
  const int kg = lane >> 4;
  const int qrow0 = qb0 + wq * 16;

  bf16x8 qf[2];
  {
    const u16* qp = qb + ((size_t)(b * TSEQ + qrow0 + r16)) * DIMQ + h * HD + kg * 8;
    qf[0] = *(const bf16x8*)(qp);
    qf[1] = *(const bf16x8*)(qp + 32);
  }
  f32x4 acc[4];
#pragma unroll
  for (int db = 0; db < 4; db++) acc[db] = (f32x4){0.f, 0.f, 0.f, 0.f};
  float m_run[4], l_run[4];
#pragma unroll
  for (int i = 0; i < 4; i++) { m_run[i] = -3.0e38f; l_run[i] = 0.f; }

  const int skey = tid >> 3, sslot = tid & 7;
  const int sd = tid >> 2, sko = tid & 3;
  const u16* kgb = kb + (size_t)(b * TSEQ) * DIMQ + h * HD;
  const u16* vgb = vbT + (size_t)(h * HD) * NTOK + (size_t)b * TSEQ;

  const int nt = (qb0 + 64) >> 5;
  for (int kt = 0; kt < nt; kt++) {
    const int k0g = kt * 32;
    __syncthreads();
    {
      uint4 kv = *(const uint4*)(kgb + (size_t)(k0g + skey) * DIMQ + sslot * 8);
      *(uint4*)(&Ks[skey * 64 + ((sslot ^ (skey & 7)) * 8)]) = kv;
      uint4 vv = *(const uint4*)(vgb + (size_t)sd * NTOK + k0g + sko * 8);
      *(uint4*)(&VTs[sd * 32 + ((sko ^ (sd & 3)) * 8)]) = vv;
      if (tid < 32) mbias[tid] = amask[b * TSEQ + k0g + tid] ? 0.f : -1e9f;
    }
    __syncthreads();
    if (k0g < qrow0 + 16) {
      f32x4 s0 = (f32x4){0.f, 0.f, 0.f, 0.f};
      f32x4 s1 = (f32x4){0.f, 0.f, 0.f, 0.f};
      {
        int key0 = r16;
        bf16x8 ka = *(const bf16x8*)(&Ks[key0 * 64 + ((kg ^ (key0 & 7)) * 8)]);
        bf16x8 kb2 = *(const bf16x8*)(&Ks[key0 * 64 + (((4 + kg) ^ (key0 & 7)) * 8)]);
        s0 = __builtin_amdgcn_mfma_f32_16x16x32_bf16(qf[0], ka, s0, 0, 0, 0);
        s0 = __builtin_amdgcn_mfma_f32_16x16x32_bf16(qf[1], kb2, s0, 0, 0, 0);
        int key1 = 16 + r16;
        bf16x8 kc = *(const bf16x8*)(&Ks[key1 * 64 + ((kg ^ (key1 & 7)) * 8)]);
        bf16x8 kd = *(const bf16x8*)(&Ks[key1 * 64 + (((4 + kg) ^ (key1 & 7)) * 8)]);
        s1 = __builtin_amdgcn_mfma_f32_16x16x32_bf16(qf[0], kc, s1, 0, 0, 0);
        s1 = __builtin_amdgcn_mfma_f32_16x16x32_bf16(qf[1], kd, s1, 0, 0, 0);
      }
      float sv0[4], sv1[4], tm[4];
      float mb0 = mbias[r16], mb1 = mbias[16 + r16];
#pragma unroll
      for (int i = 0; i < 4; i++) {
        int qg = qrow0 + kg * 4 + i;
        float a = s0[i] * 0.125f + mb0;
        float c = s1[i] * 0.125f + mb1;
        if (k0g + r16 > qg)      a = -3.0e38f;
        if (k0g + 16 + r16 > qg) c = -3.0e38f;
        sv0[i] = a; sv1[i] = c;
        tm[i] = fmaxf(a, c);
      }
#pragma unroll
      for (int mk = 1; mk < 16; mk <<= 1) {
#pragma unroll
        for (int i = 0; i < 4; i++) tm[i] = fmaxf(tm[i], __shfl_xor(tm[i], mk));
      }
      float pr0[4], pr1[4];
#pragma unroll
      for (int i = 0; i < 4; i++) {
        float nm = fmaxf(m_run[i], tm[i]);
        float sc = __expf(m_run[i] - nm);
        m_run[i] = nm;
        pr0[i] = __expf(sv0[i] - nm);
        pr1[i] = __expf(sv1[i] - nm);
        l_run[i] = l_run[i] * sc + pr0[i] + pr1[i];
#pragma unroll
        for (int db = 0; db < 4; db++) acc[db][i] *= sc;
      }
#pragma unroll
      for (int i = 0; i < 4; i++) {
        int qrl = kg * 4 + i;
        int sw = qrl & 3;
        Ps[wq][qrl * 32 + (((r16 >> 3) ^ sw) * 8) + (r16 & 7)] = f2bf(pr0[i]);
        Ps[wq][qrl * 32 + ((((16 + r16) >> 3) ^ sw) * 8) + (r16 & 7)] = f2bf(pr1[i]);
      }
      bf16x8 pf = *(const bf16x8*)(&Ps[wq][r16 * 32 + ((kg ^ (r16 & 3)) * 8)]);
#pragma unroll
      for (int db = 0; db < 4; db++) {
        int d = db * 16 + r16;
        bf16x8 vf = *(const bf16x8*)(&VTs[d * 32 + ((kg ^ (d & 3)) * 8)]);
        acc[db] = __builtin_amdgcn_mfma_f32_16x16x32_bf16(pf, vf, acc[db], 0, 0, 0);
      }
    }
  }
#pragma unroll
  for (int mk = 1; mk < 16; mk <<= 1) {
#pragma unroll
    for (int i = 0; i < 4; i++) l_run[i] += __shfl_xor(l_run[i], mk);
  }
#pragma unroll
  for (int i = 0; i < 4; i++) {
    float inv = 1.f / l_run[i];
    int qg = qrow0 + kg * 4 + i;
    u16* op = hb + ((size_t)(b * TSEQ + qg)) * DIMQ + h * HD + r16;
#pragma unroll
    for (int db = 0; db < 4; db++) op[db * 16] = f2bf(acc[db][i] * inv);
  }
}

// ---------------- add + layernorm (x + h) -> x1 f32 and x1b bf16 ----------------
__global__ __launch_bounds__(256) void addln_kernel(
    const float* __restrict__ xin, const u16* __restrict__ hres,
    const float* __restrict__ g, const float* __restrict__ beta,
    float* __restrict__ x1, u16* __restrict__ x1b) {
  __shared__ float red[8];
  int t = blockIdx.x;
  int d = threadIdx.x * 4;
  size_t base = (size_t)t * DIMQ + d;
  float4 xv = *(const float4*)(xin + base);
  uint2 hu = *(const uint2*)(hres + base);
  float v0 = xv.x + bf_lo(hu.x), v1 = xv.y + bf_hi(hu.x);
  float v2 = xv.z + bf_lo(hu.y), v3 = xv.w + bf_hi(hu.y);
  float s1 = v0 + v1 + v2 + v3;
  float s2 = v0 * v0 + v1 * v1 + v2 * v2 + v3 * v3;
#pragma unroll
  for (int off = 32; off; off >>= 1) {
    s1 += __shfl_down(s1, off);
    s2 += __shfl_down(s2, off);
  }
  int w = threadIdx.x >> 6;
  if ((threadIdx.x & 63) == 0) { red[w] = s1; red[4 + w] = s2; }
  __syncthreads();
  float S1 = red[0] + red[1] + red[2] + red[3];
  float S2 = red[4] + red[5] + red[6] + red[7];
  float m = S1 * (1.f / DIMQ);
  float var = S2 * (1.f / DIMQ) - m * m;
  float rs = rsqrtf(var + 1e-5f);
  float4 gv = *(const float4*)(g + d);
  float4 bv = *(const float4*)(beta + d);
  float o0 = (v0 - m) * rs * gv.x + bv.x;
  float o1 = (v1 - m) * rs * gv.y + bv.y;
  float o2 = (v2 - m) * rs * gv.z + bv.z;
  float o3 = (v3 - m) * rs * gv.w + bv.w;
  *(float4*)(x1 + base) = make_float4(o0, o1, o2, o3);
  uint2 pu;
  pu.x = (u32)f2bf(o0) | ((u32)f2bf(o1) << 16);
  pu.y = (u32)f2bf(o2) | ((u32)f2bf(o3) << 16);
  *(uint2*)(x1b + base) = pu;
}

// ---------------- router: logits, softmax, top-2 (NO global atomics) ----------------
__global__ __launch_bounds__(256) void router_kernel(
    const float* __restrict__ x1, const float* __restrict__ rw,
    const float* __restrict__ rb, int* __restrict__ topi,
    float* __restrict__ gkout, float* __restrict__ probs) {
  int t = blockIdx.x * 4 + (threadIdx.x >> 6);
  int l = threadIdx.x & 63;
  float acc[8];
#pragma unroll
  for (int e = 0; e < 8; e++) acc[e] = 0.f;
  const float* xr = x1 + (size_t)t * DIMQ;
  for (int k = l; k < DIMQ; k += 64) {
    float xv = xr[k];
    const float* w = rw + (size_t)k * 8;
#pragma unroll
    for (int e = 0; e < 8; e++) acc[e] += xv * w[e];
  }
#pragma unroll
  for (int e = 0; e < 8; e++) {
#pragma unroll
    for (int off = 32; off; off >>= 1) acc[e] += __shfl_down(acc[e], off);
  }
  if (l == 0) {
    float lg[8], p[8];
    float mx = -3e38f;
#pragma unroll
    for (int e = 0; e < 8; e++) { lg[e] = acc[e] + rb[e]; mx = fmaxf(mx, lg[e]); }
    float sum = 0.f;
#pragma unroll
    for (int e = 0; e < 8; e++) { p[e] = expf(lg[e] - mx); sum += p[e]; }
    float isum = 1.f / sum;
#pragma unroll
    for (int e = 0; e < 8; e++) p[e] *= isum;
    int e0 = 0;
#pragma unroll
    for (int e = 1; e < 8; e++) if (p[e] > p[e0]) e0 = e;
    int e1 = (e0 == 0) ? 1 : 0;
#pragma unroll
    for (int e = 0; e < 8; e++) if (e != e0 && p[e] > p[e1]) e1 = e;
    float s2 = p[e0] + p[e1];
    topi[2 * t] = e0; topi[2 * t + 1] = e1;
    gkout[2 * t] = p[e0] / s2; gkout[2 * t + 1] = p[e1] / s2;
    float* pp = probs + (size_t)t * 8;
#pragma unroll
    for (int e = 0; e < 8; e++) pp[e] = p[e];
  }
}

// ---------------- stats: cnt[e], Psum[e] with block-aggregated atomics ----------------
__global__ __launch_bounds__(256) void stats_kernel(
    const float* __restrict__ probs, const int* __restrict__ topi,
    int* __restrict__ cnt, float* __restrict__ Psum) {
  __shared__ float sps[4][8];
  __shared__ int   slc[4][8];
  float ps[8];
  int lc[8];
#pragma unroll
  for (int e = 0; e < 8; e++) { ps[e] = 0.f; lc[e] = 0; }
  int t = blockIdx.x * 256 + threadIdx.x;
  {
    const float* p = probs + (size_t)t * 8;
#pragma unroll
    for (int e = 0; e < 8; e++) ps[e] += p[e];
    lc[topi[2 * t]]++;
    lc[topi[2 * t + 1]]++;
  }
#pragma unroll
  for (int e = 0; e < 8; e++) {
#pragma unroll
    for (int off = 32; off; off >>= 1) {
      ps[e] += __shfl_down(ps[e], off);
      lc[e] += __shfl_down(lc[e], off);
    }
  }
  int w = threadIdx.x >> 6;
  if ((threadIdx.x & 63) == 0) {
#pragma unroll
    for (int e = 0; e < 8; e++) { sps[w][e] = ps[e]; slc[w][e] = lc[e]; }
  }
  __syncthreads();
  if (threadIdx.x < 8) {
    float fp = sps[0][threadIdx.x] + sps[1][threadIdx.x] + sps[2][threadIdx.x] + sps[3][threadIdx.x];
    int   fc = slc[0][threadIdx.x] + slc[1][threadIdx.x] + slc[2][threadIdx.x] + slc[3][threadIdx.x];
    atomicAdd(&Psum[threadIdx.x], fp);
    atomicAdd(&cnt[threadIdx.x], fc);
  }
}

__global__ void offsets_kernel(const int* __restrict__ cnt, const float* __restrict__ Psum,
                               int* __restrict__ off, int* __restrict__ fill,
                               float* __restrict__ lb_out) {
  if (threadIdx.x == 0 && blockIdx.x == 0) {
    int o = 0;
    float lb = 0.f;
    for (int e = 0; e < NEXP; e++) {
      off[e] = o;
      fill[e] = o;
      o += cnt[e];
      lb += ((float)cnt[e] / (float)NTOK) * (Psum[e] / (float)NTOK);
    }
    lb_out[0] = (float)NEXP * lb;
  }
}

// ---------------- listbuild: block-aggregated slot assignment ----------------
__global__ __launch_bounds__(256) void listbuild_kernel(
    const int* __restrict__ topi, int* fill, int* __restrict__ idxlist,
    int* __restrict__ posmap) {
  __shared__ int bcnt[8];
  __shared__ int base[8];
  __shared__ int bofs[8];
  int t = blockIdx.x * 256 + threadIdx.x;
  if (threadIdx.x < 8) { bcnt[threadIdx.x] = 0; bofs[threadIdx.x] = 0; }
  __syncthreads();
  int e0 = topi[2 * t], e1 = topi[2 * t + 1];
  atomicAdd(&bcnt[e0], 1);
  atomicAdd(&bcnt[e1], 1);
  __syncthreads();
  if (threadIdx.x < 8) base[threadIdx.x] = atomicAdd(&fill[threadIdx.x], bcnt[threadIdx.x]);
  __syncthreads();
  int s0 = base[e0] + atomicAdd(&bofs[e0], 1);
  idxlist[s0] = t;
  posmap[2 * t] = s0;
  int s1 = base[e1] + atomicAdd(&bofs[e1], 1);
  idxlist[s1] = t;
  posmap[2 * t + 1] = s1;
}

// ---------------- final: out = LN(x1 + g0*yslot[p0] + g1*yslot[p1]) ----------------
__global__ __launch_bounds__(256) void finalln_kernel(
    const float* __restrict__ x1, const u16* __restrict__ yslot,
    const int* __restrict__ posmap, const float* __restrict__ gkv,
    const float* __restrict__ g, const float* __restrict__ beta,
    float* __restrict__ out) {
  __shared__ float red[8];
  int t = blockIdx.x;
  int p0 = posmap[2 * t], p1 = posmap[2 * t + 1];
  float g0 = gkv[2 * t], g1 = gkv[2 * t + 1];
  int d = threadIdx.x * 4;
  size_t base = (size_t)t * DIMQ + d;
  float4 xv = *(const float4*)(x1 + base);
  uint2 y0 = *(const uint2*)(yslot + (size_t)p0 * DIMQ + d);
  uint2 y1 = *(const uint2*)(yslot + (size_t)p1 * DIMQ + d);
  float v0 = xv.x + g0 * bf_lo(y0.x) + g1 * bf_lo(y1.x);
  float v1 = xv.y + g0 * bf_hi(y0.x) + g1 * bf_hi(y1.x);
  float v2 = xv.z + g0 * bf_lo(y0.y) + g1 * bf_lo(y1.y);
  float v3 = xv.w + g0 * bf_hi(y0.y) + g1 * bf_hi(y1.y);
  float s1 = v0 + v1 + v2 + v3;
  float s2 = v0 * v0 + v1 * v1 + v2 * v2 + v3 * v3;
#pragma unroll
  for (int off = 32; off; off >>= 1) {
    s1 += __shfl_down(s1, off);
    s2 += __shfl_down(s2, off);
  }
  int w = threadIdx.x >> 6;
  if ((threadIdx.x & 63) == 0) { red[w] = s1; red[4 + w] = s2; }
  __syncthreads();
  float S1 = red[0] + red[1] + red[2] + red[3];
  float S2 = red[4] + red[5] + red[6] + red[7];
  float m = S1 * (1.f / DIMQ);
  float var = S2 * (1.f / DIMQ) - m * m;
  float rs = rsqrtf(var + 1e-5f);
  float4 gv = *(const float4*)(g + d);
  float4 bv = *(const float4*)(beta + d);
  float4 o;
  o.x = (v0 - m) * rs * gv.x + bv.x;
  o.y = (v1 - m) * rs * gv.y + bv.y;
  o.z = (v2 - m) * rs * gv.z + bv.z;
  o.w = (v3 - m) * rs * gv.w + bv.w;
  *(float4*)(out + base) = o;
}

// ---------------- host launch ----------------
extern "C" void kernel_launch(void* const* d_in, const int* in_sizes, int n_in,
                              void* d_out, int out_size, void* d_ws, size_t ws_size,
                              hipStream_t stream) {
  const float* x     = (const float*)d_in[0];
  const int*   amask = (const int*)d_in[1];
  const float* Wq    = (const float*)d_in[2];
  const float* bq    = (const float*)d_in[3];
  const float* Wk    = (const float*)d_in[4];
  const float* bk    = (const float*)d_in[5];
  const float* Wv    = (const float*)d_in[6];
  const float* bv    = (const float*)d_in[7];
  const float* Wo    = (const float*)d_in[8];
  const float* bo    = (const float*)d_in[9];
  const float* g1    = (const float*)d_in[10];
  const float* beta1 = (const float*)d_in[11];
  const float* rw    = (const float*)d_in[12];
  const float* rb    = (const float*)d_in[13];
  const float* W1    = (const float*)d_in[14];
  const float* B1    = (const float*)d_in[15];
  const float* W2    = (const float*)d_in[16];
  const float* B2    = (const float*)d_in[17];
  const float* g2    = (const float*)d_in[18];
  const float* beta2 = (const float*)d_in[19];
  float* out    = (float*)d_out;
  float* lb_out = out + (size_t)NTOK * DIMQ;

  char* ws = (char*)d_ws;
  size_t off_acc = 0;
  auto alloc = [&](size_t bytes) {
    void* p = ws + off_acc;
    off_acc += (bytes + 255) & ~(size_t)255;
    return p;
  };
  u16* xb    = (u16*)alloc((size_t)NTOK * DIMQ * 2);
  u16* qbuf  = (u16*)alloc((size_t)NTOK * DIMQ * 2);
  u16* kbuf  = (u16*)alloc((size_t)NTOK * DIMQ * 2);
  u16* vbufT = (u16*)alloc((size_t)NTOK * DIMQ * 2);  // transposed: [col][row]
  u16* hb    = (u16*)alloc((size_t)NTOK * DIMQ * 2);
  u16* ho    = (u16*)alloc((size_t)NTOK * DIMQ * 2);
  float* x1  = (float*)alloc((size_t)NTOK * DIMQ * 4);
  u16* x1b   = (u16*)alloc((size_t)NTOK * DIMQ * 2);
  u16* Wqt   = (u16*)alloc((size_t)DIMQ * DIMQ * 2);
  u16* Wkt   = (u16*)alloc((size_t)DIMQ * DIMQ * 2);
  u16* Wvt   = (u16*)alloc((size_t)DIMQ * DIMQ * 2);
  u16* Wot   = (u16*)alloc((size_t)DIMQ * DIMQ * 2);
  u16* W1t   = (u16*)alloc((size_t)NEXP * DFF * DIMQ * 2);
  u16* W2t   = (u16*)alloc((size_t)NEXP * DIMQ * DFF * 2);
  u16* he    = (u16*)alloc((size_t)2 * NTOK * DFF * 2);
  u16* yslot = (u16*)alloc((size_t)2 * NTOK * DIMQ * 2);
  char* stats = (char*)alloc(4096);
  int*   cnt   = (int*)stats;
  float* Psum  = (float*)(stats + 32);
  int*   offp  = (int*)(stats + 64);
  int*   fill  = (int*)(stats + 96);
  int* topi    = (int*)alloc((size_t)NTOK * 2 * 4);
  float* gkbuf = (float*)alloc((size_t)NTOK * 2 * 4);
  int* posmap  = (int*)alloc((size_t)NTOK * 2 * 4);
  int* idxlist = (int*)alloc((size_t)NTOK * 2 * 4);
  float* probs = (float*)alloc((size_t)NTOK * 8 * 4);

  hipMemsetAsync(stats, 0, 64, stream);

  // converts / transposes
  cvt_f32_bf16<<<NTOK * DIMQ / 1024, 256, 0, stream>>>(x, xb, NTOK * DIMQ);
  transpose_f32_bf16<<<dim3(DIMQ / 32, DIMQ / 32, 1), 256, 0, stream>>>(Wq, Wqt, DIMQ, DIMQ);
  transpose_f32_bf16<<<dim3(DIMQ / 32, DIMQ / 32, 1), 256, 0, stream>>>(Wk, Wkt, DIMQ, DIMQ);
  transpose_f32_bf16<<<dim3(DIMQ / 32, DIMQ / 32, 1), 256, 0, stream>>>(Wv, Wvt, DIMQ, DIMQ);
  transpose_f32_bf16<<<dim3(DIMQ / 32, DIMQ / 32, 1), 256, 0, stream>>>(Wo, Wot, DIMQ, DIMQ);
  transpose_f32_bf16<<<dim3(DFF / 32, DIMQ / 32, NEXP), 256, 0, stream>>>(W1, W1t, DIMQ, DFF);
  transpose_f32_bf16<<<dim3(DIMQ / 32, DFF / 32, NEXP), 256, 0, stream>>>(W2, W2t, DFF, DIMQ);

  // attention path
  dim3 gproj(DIMQ / 128, NTOK / 128);
  gemm_bt_kernel<<<gproj, 256, 0, stream>>>(xb, Wqt, bq, qbuf, NTOK, DIMQ, DIMQ);
  gemm_bt_kernel<<<gproj, 256, 0, stream>>>(xb, Wkt, bk, kbuf, NTOK, DIMQ, DIMQ);
  gemm_bt_tc_kernel<<<gproj, 256, 0, stream>>>(xb, Wvt, bv, vbufT, NTOK, DIMQ, DIMQ);
  attn_mfma_kernel<<<dim3(TSEQ / 64, BATCH * NHEADS), 256, 0, stream>>>(qbuf, kbuf, vbufT, amask, hb);
  gemm_bt_kernel<<<gproj, 256, 0, stream>>>(hb, Wot, bo, ho, NTOK, DIMQ, DIMQ);
  addln_kernel<<<NTOK, 256, 0, stream>>>(x, ho, g1, beta1, x1, x1b);

  // MoE path
  router_kernel<<<NTOK / 4, 256, 0, stream>>>(x1, rw, rb, topi, gkbuf, probs);
  stats_kernel<<<NTOK / 256, 256, 0, stream>>>(probs, topi, cnt, Psum);
  offsets_kernel<<<1, 64, 0, stream>>>(cnt, Psum, offp, fill, lb_out);
  listbuild_kernel<<<NTOK / 256, 256, 0, stream>>>(topi, fill, idxlist, posmap);
  moe_gemm1_kernel<<<dim3(DFF / 128, NTOK / 128, NEXP), 256, 0, stream>>>(x1b, W1t, B1, he, cnt, offp, idxlist);
  moe_gemm2_kernel<<<dim3(DIMQ / 128, NTOK / 128, NEXP), 256, 0, stream>>>(he, W2t, B2, yslot, cnt, offp);
  finalln_kernel<<<NTOK, 256, 0, stream>>>(x1, yslot, posmap, gkbuf, g2, beta2, out);
}

// Round 5
// 898.414 us; speedup vs baseline: 4.0253x; 1.0401x over previous
//
#include <hip/hip_runtime.h>
#include <hip/hip_bf16.h>
#include <stdint.h>

#define DIMQ   1024
#define NHEADS 16
#define HD     64
#define NEXP   8
#define DFF    4096
#define NTOK   8192
#define TSEQ   1024
#define BATCH  8

typedef unsigned short u16;
typedef unsigned int   u32;
typedef __attribute__((ext_vector_type(8))) short bf16x8;
typedef __attribute__((ext_vector_type(4))) float f32x4;

__device__ __forceinline__ float bf_lo(u32 w) { return __uint_as_float(w << 16); }
__device__ __forceinline__ float bf_hi(u32 w) { return __uint_as_float(w & 0xffff0000u); }
__device__ __forceinline__ u16 f2bf(float f) {
  u32 x = __float_as_uint(f);
  return (u16)((x + 0x7fffu + ((x >> 16) & 1u)) >> 16);
}

// async 16B global -> LDS (linear dest: wave base + lane*16)
__device__ __forceinline__ void gload16(const u16* g, u16* l) {
  __builtin_amdgcn_global_load_lds((const __attribute__((address_space(1))) u32*)g,
                                   (__attribute__((address_space(3))) u32*)l, 16, 0, 0);
}

// ---------------- convert f32 -> bf16 ----------------
__global__ __launch_bounds__(256) void cvt_f32_bf16(const float* __restrict__ in,
                                                    u16* __restrict__ out, int n) {
  int i = (blockIdx.x * 256 + threadIdx.x) * 4;
  if (i >= n) return;
  float4 v = *(const float4*)(in + i);
  ushort4 o;
  o.x = f2bf(v.x); o.y = f2bf(v.y); o.z = f2bf(v.z); o.w = f2bf(v.w);
  *(ushort4*)(out + i) = o;
}

// ---------------- batched transpose f32[R][C] -> bf16[C][R] ----------------
__global__ __launch_bounds__(256) void transpose_f32_bf16(
    const float* __restrict__ in, u16* __restrict__ out, int R, int C) {
  __shared__ float tile[32][33];
  size_t base = (size_t)blockIdx.z * (size_t)R * (size_t)C;
  int tx = threadIdx.x & 31, ty = threadIdx.x >> 5;
  int c = blockIdx.x * 32 + tx;
#pragma unroll
  for (int i = 0; i < 4; i++) {
    int r = blockIdx.y * 32 + ty + i * 8;
    tile[ty + i * 8][tx] = in[base + (size_t)r * C + c];
  }
  __syncthreads();
  int rr = blockIdx.y * 32 + tx;
#pragma unroll
  for (int i = 0; i < 4; i++) {
    int cc = blockIdx.x * 32 + ty + i * 8;
    out[base + (size_t)cc * R + rr] = f2bf(tile[tx][ty + i * 8]);
  }
}

// ---------------- 128x128 MFMA GEMM core (projections) ----------------
template <bool GATHER, bool RELU, bool TRANSC>
__device__ __forceinline__ void gemm_core(
    const u16* __restrict__ A, const u16* __restrict__ Bt,
    const float* __restrict__ bias, u16* __restrict__ C,
    int M, int N, int K, const int* __restrict__ gidx) {
  __shared__ u16 As[128 * 32];
  __shared__ u16 Bs[128 * 32];
  const int tid = threadIdx.x;
  const int lane = tid & 63;
  const int wave = tid >> 6;
  const int wr = wave >> 1, wc = wave & 1;
  const int lr = lane & 15, kg = lane >> 4;
  const int rowbase = blockIdx.y * 128;
  const int colbase = blockIdx.x * 128;

  f32x4 acc[4][4];
#pragma unroll
  for (int m = 0; m < 4; m++)
#pragma unroll
    for (int n = 0; n < 4; n++) acc[m][n] = (f32x4){0.f, 0.f, 0.f, 0.f};

  const int r0 = tid >> 2, seg = tid & 3;
  const int slog = seg ^ ((r0 >> 1) & 3);
  int ar0 = rowbase + r0;      if (ar0 >= M) ar0 = M - 1;
  int ar1 = rowbase + r0 + 64; if (ar1 >= M) ar1 = M - 1;
  const long arow0 = GATHER ? gidx[ar0] : ar0;
  const long arow1 = GATHER ? gidx[ar1] : ar1;
  const u16* Aptr0 = A + (size_t)arow0 * K + slog * 8;
  const u16* Aptr1 = A + (size_t)arow1 * K + slog * 8;
  const u16* Bptr0 = Bt + (size_t)(colbase + r0) * K + slog * 8;
  const u16* Bptr1 = Bt + (size_t)(colbase + r0 + 64) * K + slog * 8;
  u16* ldsA0 = &As[tid * 8];
  u16* ldsA1 = &As[2048 + tid * 8];
  u16* ldsB0 = &Bs[tid * 8];
  u16* ldsB1 = &Bs[2048 + tid * 8];

  const int swz = (lr >> 1) & 3;

  for (int k0 = 0; k0 < K; k0 += 32) {
    gload16(Aptr0 + k0, ldsA0);
    gload16(Aptr1 + k0, ldsA1);
    gload16(Bptr0 + k0, ldsB0);
    gload16(Bptr1 + k0, ldsB1);
    __syncthreads();
    bf16x8 af[4], bfr[4];
#pragma unroll
    for (int m = 0; m < 4; m++)
      af[m] = *(const bf16x8*)(&As[(wr * 64 + m * 16 + lr) * 32 + ((kg ^ swz) * 8)]);
#pragma unroll
    for (int n = 0; n < 4; n++)
      bfr[n] = *(const bf16x8*)(&Bs[(wc * 64 + n * 16 + lr) * 32 + ((kg ^ swz) * 8)]);
#pragma unroll
    for (int m = 0; m < 4; m++)
#pragma unroll
      for (int n = 0; n < 4; n++)
        acc[m][n] = __builtin_amdgcn_mfma_f32_16x16x32_bf16(af[m], bfr[n], acc[m][n], 0, 0, 0);
    __syncthreads();
  }
#pragma unroll
  for (int n = 0; n < 4; n++) {
    int col = colbase + wc * 64 + n * 16 + lr;
    float bv = bias[col];
#pragma unroll
    for (int m = 0; m < 4; m++) {
      int row0 = rowbase + wr * 64 + m * 16 + kg * 4;
      if (TRANSC) {
        if (row0 + 3 < M) {
          ushort4 pk;
          pk.x = f2bf(acc[m][n][0] + bv);
          pk.y = f2bf(acc[m][n][1] + bv);
          pk.z = f2bf(acc[m][n][2] + bv);
          pk.w = f2bf(acc[m][n][3] + bv);
          *(ushort4*)(&C[(size_t)col * M + row0]) = pk;
        } else {
#pragma unroll
          for (int r = 0; r < 4; r++)
            if (row0 + r < M) C[(size_t)col * M + row0 + r] = f2bf(acc[m][n][r] + bv);
        }
      } else {
#pragma unroll
        for (int r = 0; r < 4; r++) {
          int row = row0 + r;
          if (row < M) {
            float v = acc[m][n][r] + bv;
            if (RELU) v = fmaxf(v, 0.f);
            C[(size_t)row * N + col] = f2bf(v);
          }
        }
      }
    }
  }
}

__global__ __launch_bounds__(256) void gemm_bt_kernel(
    const u16* __restrict__ A, const u16* __restrict__ Bt,
    const float* __restrict__ bias, u16* __restrict__ C, int M, int N, int K) {
  gemm_core<false, false, false>(A, Bt, bias, C, M, N, K, nullptr);
}

__global__ __launch_bounds__(256) void gemm_bt_tc_kernel(
    const u16* __restrict__ A, const u16* __restrict__ Bt,
    const float* __restrict__ bias, u16* __restrict__ C, int M, int N, int K) {
  gemm_core<false, false, true>(A, Bt, bias, C, M, N, K, nullptr);
}

// ---------------- 256x256 2-phase MFMA GEMM core (MoE experts) ----------------
// BM=BN=256, BK=64, 512 threads = 8 waves (2Mx4N), per-wave 128x64 output.
// Double-buffered 128 KiB LDS; next K-tile staged via global_load_lds BEFORE the
// compute phase (loads overlap 64 MFMAs); ONE __syncthreads per K-tile drains.
// XOR slot swizzle (phys = log ^ (row&7)) applied on both global src and LDS read.
template <bool GATHER, bool RELU>
__device__ __forceinline__ void gemm256_core(
    const u16* __restrict__ A, const u16* __restrict__ Bt,
    const float* __restrict__ bias, u16* __restrict__ C,
    int M, int N, int K, const int* __restrict__ gidx) {
  __shared__ u16 lds[2][2][256 * 64];   // [buf][0=A,1=B][row*64 + k] : 128 KiB
  const int tid = threadIdx.x;
  const int lane = tid & 63;
  const int wave = tid >> 6;            // 0..7
  const int wr = wave >> 2;             // 0..1  M-half
  const int wcol = wave & 3;            // 0..3  N-quarter
  const int lr = lane & 15, kg = lane >> 4;
  const int rowbase = blockIdx.y * 256;
  const int colbase = blockIdx.x * 256;

  f32x4 acc[8][4];
#pragma unroll
  for (int m = 0; m < 8; m++)
#pragma unroll
    for (int n = 0; n < 4; n++) acc[m][n] = (f32x4){0.f, 0.f, 0.f, 0.f};

  // staging map: load j (0..3): position p = tid + j*512 -> row = p>>3, phys 16B slot = p&7
  // LDS offset = p*8 u16 (linear); global col slot = phys ^ (row&7)
  const int srow0 = tid >> 3, sphys = tid & 7;
  const u16* asrc[4];
  const u16* bsrc[4];
#pragma unroll
  for (int j = 0; j < 4; j++) {
    int row = srow0 + j * 64;
    int ls = sphys ^ (row & 7);
    int ar = rowbase + row; if (ar >= M) ar = M - 1;
    long ga = GATHER ? gidx[ar] : ar;
    asrc[j] = A + (size_t)ga * K + ls * 8;
    bsrc[j] = Bt + (size_t)(colbase + row) * K + ls * 8;
  }

#define STAGE256(buf, k0)                                              \
  {                                                                    \
    _Pragma("unroll")                                                  \
    for (int j = 0; j < 4; j++) {                                      \
      gload16(asrc[j] + (k0), &lds[buf][0][tid * 8 + j * 4096]);       \
      gload16(bsrc[j] + (k0), &lds[buf][1][tid * 8 + j * 4096]);       \
    }                                                                  \
  }

  STAGE256(0, 0);
  __syncthreads();
  const int NT = K >> 6;
  for (int t = 0; t < NT; t++) {
    const int buf = t & 1;
    if (t + 1 < NT) STAGE256(buf ^ 1, (t + 1) << 6);
    bf16x8 bfr[4][2];
#pragma unroll
    for (int nr = 0; nr < 4; nr++) {
      int rb = wcol * 64 + nr * 16 + lr;
#pragma unroll
      for (int kk = 0; kk < 2; kk++)
        bfr[nr][kk] = *(const bf16x8*)(&lds[buf][1][rb * 64 + (((kk * 4 + kg) ^ (rb & 7)) * 8)]);
    }
#pragma unroll
    for (int mr = 0; mr < 8; mr++) {
      int ra = wr * 128 + mr * 16 + lr;
      bf16x8 a0 = *(const bf16x8*)(&lds[buf][0][ra * 64 + ((kg ^ (ra & 7)) * 8)]);
      bf16x8 a1 = *(const bf16x8*)(&lds[buf][0][ra * 64 + (((4 + kg) ^ (ra & 7)) * 8)]);
#pragma unroll
      for (int nr = 0; nr < 4; nr++) {
        acc[mr][nr] = __builtin_amdgcn_mfma_f32_16x16x32_bf16(a0, bfr[nr][0], acc[mr][nr], 0, 0, 0);
        acc[mr][nr] = __builtin_amdgcn_mfma_f32_16x16x32_bf16(a1, bfr[nr][1], acc[mr][nr], 0, 0, 0);
      }
    }
    __syncthreads();   // drains vmcnt(0): next tile's staged data visible; buf reusable
  }
#undef STAGE256

  // epilogue: C/D layout col=lane&15, row=(lane>>4)*4+reg
#pragma unroll
  for (int nr = 0; nr < 4; nr++) {
    int col = colbase + wcol * 64 + nr * 16 + lr;
    float bv = bias[col];
#pragma unroll
    for (int mr = 0; mr < 8; mr++) {
      int row0 = rowbase + wr * 128 + mr * 16 + kg * 4;
#pragma unroll
      for (int r = 0; r < 4; r++) {
        int row = row0 + r;
        if (row < M) {
          float v = acc[mr][nr][r] + bv;
          if (RELU) v = fmaxf(v, 0.f);
          C[(size_t)row * N + col] = f2bf(v);
        }
      }
    }
  }
}

__global__ __launch_bounds__(512, 2) void moe_gemm1_kernel(
    const u16* __restrict__ x1b, const u16* __restrict__ W1t,
    const float* __restrict__ B1, u16* __restrict__ he,
    const int* __restrict__ cnt, const int* __restrict__ off,
    const int* __restrict__ idxlist) {
  int e = blockIdx.z;
  int M = cnt[e];
  if ((int)blockIdx.y * 256 >= M) return;
  gemm256_core<true, true>(x1b, W1t + (size_t)e * DFF * DIMQ, B1 + e * DFF,
                           he + (size_t)off[e] * DFF, M, DFF, DIMQ, idxlist + off[e]);
}

__global__ __launch_bounds__(512, 2) void moe_gemm2_kernel(
    const u16* __restrict__ he, const u16* __restrict__ W2t,
    const float* __restrict__ B2, u16* __restrict__ yslot,
    const int* __restrict__ cnt, const int* __restrict__ off) {
  int e = blockIdx.z;
  int M = cnt[e];
  if ((int)blockIdx.y * 256 >= M) return;
  gemm256_core<false, false>(he + (size_t)off[e] * DFF, W2t + (size_t)e * DIMQ * DFF,
                             B2 + e * DIMQ, yslot + (size_t)off[e] * DIMQ, M, DIMQ, DFF, nullptr);
}

// ---------------- MFMA flash attention ----------------
__global__ __launch_bounds__(256) void attn_mfma_kernel(
    const u16* __restrict__ qb, const u16* __restrict__ kb,
    const u16* __restrict__ vbT, const int* __restrict__ amask,
    u16* __restrict__ hb) {
  __shared__ u16 Ks[32 * 64];
  __shared__ u16 VTs[64 * 32];
  __shared__ u16 Ps[4][16 * 32];
  __shared__ float mbias[32];

  const int b = blockIdx.y >> 4;
  const int h = blockIdx.y & 15;
  const int qb0 = blockIdx.x * 64;
  const int tid = threadIdx.x;
  const int lane = tid & 63;
  const int wq = tid >> 6;
  const int r16 = lane & 15;
  const int kg = lane >> 4;
  const int qrow0 = qb0 + wq * 16;

  bf16x8 qf[2];
  {
    const u16* qp = qb + ((size_t)(b * TSEQ + qrow0 + r16)) * DIMQ + h * HD + kg * 8;
    qf[0] = *(const bf16x8*)(qp);
    qf[1] = *(const bf16x8*)(qp + 32);
  }
  f32x4 acc[4];
#pragma unroll
  for (int db = 0; db < 4; db++) acc[db] = (f32x4){0.f, 0.f, 0.f, 0.f};
  float m_run[4], l_run[4];
#pragma unroll
  for (int i = 0; i < 4; i++) { m_run[i] = -3.0e38f; l_run[i] = 0.f; }

  const int skey = tid >> 3, sslot = tid & 7;
  const int sd = tid >> 2, sko = tid & 3;
  const u16* kgb = kb + (size_t)(b * TSEQ) * DIMQ + h * HD;
  const u16* vgb = vbT + (size_t)(h * HD) * NTOK + (size_t)b * TSEQ;

  const int nt = (qb0 + 64) >> 5;
  for (int kt = 0; kt < nt; kt++) {
    const int k0g = kt * 32;
    __syncthreads();
    {
      uint4 kv = *(const uint4*)(kgb + (size_t)(k0g + skey) * DIMQ + sslot * 8);
      *(uint4*)(&Ks[skey * 64 + ((sslot ^ (skey & 7)) * 8)]) = kv;
      uint4 vv = *(const uint4*)(vgb + (size_t)sd * NTOK + k0g + sko * 8);
      *(uint4*)(&VTs[sd * 32 + ((sko ^ (sd & 3)) * 8)]) = vv;
      if (tid < 32) mbias[tid] = amask[b * TSEQ + k0g + tid] ? 0.f : -1e9f;
    }
    __syncthreads();
    if (k0g < qrow0 + 16) {
      f32x4 s0 = (f32x4){0.f, 0.f, 0.f, 0.f};
      f32x4 s1 = (f32x4){0.f, 0.f, 0.f, 0.f};
      {
        int key0 = r16;
        bf16x8 ka = *(const bf16x8*)(&Ks[key0 * 64 + ((kg ^ (key0 & 7)) * 8)]);
        bf16x8 kb2 = *(const bf16x8*)(&Ks[key0 * 64 + (((4 + kg) ^ (key0 & 7)) * 8)]);
        s0 = __builtin_amdgcn_mfma_f32_16x16x32_bf16(qf[0], ka, s0, 0, 0, 0);
        s0 = __builtin_amdgcn_mfma_f32_16x16x32_bf16(qf[1], kb2, s0, 0, 0, 0);
        int key1 = 16 + r16;
        bf16x8 kc = *(const bf16x8*)(&Ks[key1 * 64 + ((kg ^ (key1 & 7)) * 8)]);
        bf16x8 kd = *(const bf16x8*)(&Ks[key1 * 64 + (((4 + kg) ^ (key1 & 7)) * 8)]);
        s1 = __builtin_amdgcn_mfma_f32_16x16x32_bf16(qf[0], kc, s1, 0, 0, 0);
        s1 = __builtin_amdgcn_mfma_f32_16x16x32_bf16(qf[1], kd, s1, 0, 0, 0);
      }
      float sv0[4], sv1[4], tm[4];
      float mb0 = mbias[r16], mb1 = mbias[16 + r16];
#pragma unroll
      for (int i = 0; i < 4; i++) {
        int qg = qrow0 + kg * 4 + i;
        float a = s0[i] * 0.125f + mb0;
        float c = s1[i] * 0.125f + mb1;
        if (k0g + r16 > qg)      a = -3.0e38f;
        if (k0g + 16 + r16 > qg) c = -3.0e38f;
        sv0[i] = a; sv1[i] = c;
        tm[i] = fmaxf(a, c);
      }
#pragma unroll
      for (int mk = 1; mk < 16; mk <<= 1) {
#pragma unroll
        for (int i = 0; i < 4; i++) tm[i] = fmaxf(tm[i], __shfl_xor(tm[i], mk));
      }
      float pr0[4], pr1[4];
#pragma unroll
      for (int i = 0; i < 4; i++) {
        float nm = fmaxf(m_run[i], tm[i]);
        float sc = __expf(m_run[i] - nm);
        m_run[i] = nm;
        pr0[i] = __expf(sv0[i] - nm);
        pr1[i] = __expf(sv1[i] - nm);
        l_run[i] = l_run[i] * sc + pr0[i] + pr1[i];
#pragma unroll
        for (int db = 0; db < 4; db++) acc[db][i] *= sc;
      }
#pragma unroll
      for (int i = 0; i < 4; i++) {
        int qrl = kg * 4 + i;
        int sw = qrl & 3;
        Ps[wq][qrl * 32 + (((r16 >> 3) ^ sw) * 8) + (r16 & 7)] = f2bf(pr0[i]);
        Ps[wq][qrl * 32 + ((((16 + r16) >> 3) ^ sw) * 8) + (r16 & 7)] = f2bf(pr1[i]);
      }
      bf16x8 pf = *(const bf16x8*)(&Ps[wq][r16 * 32 + ((kg ^ (r16 & 3)) * 8)]);
#pragma unroll
      for (int db = 0; db < 4; db++) {
        int d = db * 16 + r16;
        bf16x8 vf = *(const bf16x8*)(&VTs[d * 32 + ((kg ^ (d & 3)) * 8)]);
        acc[db] = __builtin_amdgcn_mfma_f32_16x16x32_bf16(pf, vf, acc[db], 0, 0, 0);
      }
    }
  }
#pragma unroll
  for (int mk = 1; mk < 16; mk <<= 1) {
#pragma unroll
    for (int i = 0; i < 4; i++) l_run[i] += __shfl_xor(l_run[i], mk);
  }
#pragma unroll
  for (int i = 0; i < 4; i++) {
    float inv = 1.f / l_run[i];
    int qg = qrow0 + kg * 4 + i;
    u16* op = hb + ((size_t)(b * TSEQ + qg)) * DIMQ + h * HD + r16;
#pragma unroll
    for (int db = 0; db < 4; db++) op[db * 16] = f2bf(acc[db][i] * inv);
  }
}

// ---------------- add + layernorm (x + h) -> x1 f32 and x1b bf16 ----------------
__global__ __launch_bounds__(256) void addln_kernel(
    const float* __restrict__ xin, const u16* __restrict__ hres,
    const float* __restrict__ g, const float* __restrict__ beta,
    float* __restrict__ x1, u16* __restrict__ x1b) {
  __shared__ float red[8];
  int t = blockIdx.x;
  int d = threadIdx.x * 4;
  size_t base = (size_t)t * DIMQ + d;
  float4 xv = *(const float4*)(xin + base);
  uint2 hu = *(const uint2*)(hres + base);
  float v0 = xv.x + bf_lo(hu.x), v1 = xv.y + bf_hi(hu.x);
  float v2 = xv.z + bf_lo(hu.y), v3 = xv.w + bf_hi(hu.y);
  float s1 = v0 + v1 + v2 + v3;
  float s2 = v0 * v0 + v1 * v1 + v2 * v2 + v3 * v3;
#pragma unroll
  for (int off = 32; off; off >>= 1) {
    s1 += __shfl_down(s1, off);
    s2 += __shfl_down(s2, off);
  }
  int w = threadIdx.x >> 6;
  if ((threadIdx.x & 63) == 0) { red[w] = s1; red[4 + w] = s2; }
  __syncthreads();
  float S1 = red[0] + red[1] + red[2] + red[3];
  float S2 = red[4] + red[5] + red[6] + red[7];
  float m = S1 * (1.f / DIMQ);
  float var = S2 * (1.f / DIMQ) - m * m;
  float rs = rsqrtf(var + 1e-5f);
  float4 gv = *(const float4*)(g + d);
  float4 bv = *(const float4*)(beta + d);
  float o0 = (v0 - m) * rs * gv.x + bv.x;
  float o1 = (v1 - m) * rs * gv.y + bv.y;
  float o2 = (v2 - m) * rs * gv.z + bv.z;
  float o3 = (v3 - m) * rs * gv.w + bv.w;
  *(float4*)(x1 + base) = make_float4(o0, o1, o2, o3);
  uint2 pu;
  pu.x = (u32)f2bf(o0) | ((u32)f2bf(o1) << 16);
  pu.y = (u32)f2bf(o2) | ((u32)f2bf(o3) << 16);
  *(uint2*)(x1b + base) = pu;
}

// ---------------- router: logits, softmax, top-2 (NO global atomics) ----------------
__global__ __launch_bounds__(256) void router_kernel(
    const float* __restrict__ x1, const float* __restrict__ rw,
    const float* __restrict__ rb, int* __restrict__ topi,
    float* __restrict__ gkout, float* __restrict__ probs) {
  int t = blockIdx.x * 4 + (threadIdx.x >> 6);
  int l = threadIdx.x & 63;
  float acc[8];
#pragma unroll
  for (int e = 0; e < 8; e++) acc[e] = 0.f;
  const float* xr = x1 + (size_t)t * DIMQ;
  for (int k = l; k < DIMQ; k += 64) {
    float xv = xr[k];
    const float* w = rw + (size_t)k * 8;
#pragma unroll
    for (int e = 0; e < 8; e++) acc[e] += xv * w[e];
  }
#pragma unroll
  for (int e = 0; e < 8; e++) {
#pragma unroll
    for (int off = 32; off; off >>= 1) acc[e] += __shfl_down(acc[e], off);
  }
  if (l == 0) {
    float lg[8], p[8];
    float mx = -3e38f;
#pragma unroll
    for (int e = 0; e < 8; e++) { lg[e] = acc[e] + rb[e]; mx = fmaxf(mx, lg[e]); }
    float sum = 0.f;
#pragma unroll
    for (int e = 0; e < 8; e++) { p[e] = expf(lg[e] - mx); sum += p[e]; }
    float isum = 1.f / sum;
#pragma unroll
    for (int e = 0; e < 8; e++) p[e] *= isum;
    int e0 = 0;
#pragma unroll
    for (int e = 1; e < 8; e++) if (p[e] > p[e0]) e0 = e;
    int e1 = (e0 == 0) ? 1 : 0;
#pragma unroll
    for (int e = 0; e < 8; e++) if (e != e0 && p[e] > p[e1]) e1 = e;
    float s2 = p[e0] + p[e1];
    topi[2 * t] = e0; topi[2 * t + 1] = e1;
    gkout[2 * t] = p[e0] / s2; gkout[2 * t + 1] = p[e1] / s2;
    float* pp = probs + (size_t)t * 8;
#pragma unroll
    for (int e = 0; e < 8; e++) pp[e] = p[e];
  }
}

// ---------------- stats: cnt[e], Psum[e] with block-aggregated atomics ----------------
__global__ __launch_bounds__(256) void stats_kernel(
    const float* __restrict__ probs, const int* __restrict__ topi,
    int* __restrict__ cnt, float* __restrict__ Psum) {
  __shared__ float sps[4][8];
  __shared__ int   slc[4][8];
  float ps[8];
  int lc[8];
#pragma unroll
  for (int e = 0; e < 8; e++) { ps[e] = 0.f; lc[e] = 0; }
  int t = blockIdx.x * 256 + threadIdx.x;
  {
    const float* p = probs + (size_t)t * 8;
#pragma unroll
    for (int e = 0; e < 8; e++) ps[e] += p[e];
    lc[topi[2 * t]]++;
    lc[topi[2 * t + 1]]++;
  }
#pragma unroll
  for (int e = 0; e < 8; e++) {
#pragma unroll
    for (int off = 32; off; off >>= 1) {
      ps[e] += __shfl_down(ps[e], off);
      lc[e] += __shfl_down(lc[e], off);
    }
  }
  int w = threadIdx.x >> 6;
  if ((threadIdx.x & 63) == 0) {
#pragma unroll
    for (int e = 0; e < 8; e++) { sps[w][e] = ps[e]; slc[w][e] = lc[e]; }
  }
  __syncthreads();
  if (threadIdx.x < 8) {
    float fp = sps[0][threadIdx.x] + sps[1][threadIdx.x] + sps[2][threadIdx.x] + sps[3][threadIdx.x];
    int   fc = slc[0][threadIdx.x] + slc[1][threadIdx.x] + slc[2][threadIdx.x] + slc[3][threadIdx.x];
    atomicAdd(&Psum[threadIdx.x], fp);
    atomicAdd(&cnt[threadIdx.x], fc);
  }
}

__global__ void offsets_kernel(const int* __restrict__ cnt, const float* __restrict__ Psum,
                               int* __restrict__ off, int* __restrict__ fill,
                               float* __restrict__ lb_out) {
  if (threadIdx.x == 0 && blockIdx.x == 0) {
    int o = 0;
    float lb = 0.f;
    for (int e = 0; e < NEXP; e++) {
      off[e] = o;
      fill[e] = o;
      o += cnt[e];
      lb += ((float)cnt[e] / (float)NTOK) * (Psum[e] / (float)NTOK);
    }
    lb_out[0] = (float)NEXP * lb;
  }
}

// ---------------- listbuild: block-aggregated slot assignment ----------------
__global__ __launch_bounds__(256) void listbuild_kernel(
    const int* __restrict__ topi, int* fill, int* __restrict__ idxlist,
    int* __restrict__ posmap) {
  __shared__ int bcnt[8];
  __shared__ int base[8];
  __shared__ int bofs[8];
  int t = blockIdx.x * 256 + threadIdx.x;
  if (threadIdx.x < 8) { bcnt[threadIdx.x] = 0; bofs[threadIdx.x] = 0; }
  __syncthreads();
  int e0 = topi[2 * t], e1 = topi[2 * t + 1];
  atomicAdd(&bcnt[e0], 1);
  atomicAdd(&bcnt[e1], 1);
  __syncthreads();
  if (threadIdx.x < 8) base[threadIdx.x] = atomicAdd(&fill[threadIdx.x], bcnt[threadIdx.x]);
  __syncthreads();
  int s0 = base[e0] + atomicAdd(&bofs[e0], 1);
  idxlist[s0] = t;
  posmap[2 * t] = s0;
  int s1 = base[e1] + atomicAdd(&bofs[e1], 1);
  idxlist[s1] = t;
  posmap[2 * t + 1] = s1;
}

// ---------------- final: out = LN(x1 + g0*yslot[p0] + g1*yslot[p1]) ----------------
__global__ __launch_bounds__(256) void finalln_kernel(
    const float* __restrict__ x1, const u16* __restrict__ yslot,
    const int* __restrict__ posmap, const float* __restrict__ gkv,
    const float* __restrict__ g, const float* __restrict__ beta,
    float* __restrict__ out) {
  __shared__ float red[8];
  int t = blockIdx.x;
  int p0 = posmap[2 * t], p1 = posmap[2 * t + 1];
  float g0 = gkv[2 * t], g1 = gkv[2 * t + 1];
  int d = threadIdx.x * 4;
  size_t base = (size_t)t * DIMQ + d;
  float4 xv = *(const float4*)(x1 + base);
  uint2 y0 = *(const uint2*)(yslot + (size_t)p0 * DIMQ + d);
  uint2 y1 = *(const uint2*)(yslot + (size_t)p1 * DIMQ + d);
  float v0 = xv.x + g0 * bf_lo(y0.x) + g1 * bf_lo(y1.x);
  float v1 = xv.y + g0 * bf_hi(y0.x) + g1 * bf_hi(y1.x);
  float v2 = xv.z + g0 * bf_lo(y0.y) + g1 * bf_lo(y1.y);
  float v3 = xv.w + g0 * bf_hi(y0.y) + g1 * bf_hi(y1.y);
  float s1 = v0 + v1 + v2 + v3;
  float s2 = v0 * v0 + v1 * v1 + v2 * v2 + v3 * v3;
#pragma unroll
  for (int off = 32; off; off >>= 1) {
    s1 += __shfl_down(s1, off);
    s2 += __shfl_down(s2, off);
  }
  int w = threadIdx.x >> 6;
  if ((threadIdx.x & 63) == 0) { red[w] = s1; red[4 + w] = s2; }
  __syncthreads();
  float S1 = red[0] + red[1] + red[2] + red[3];
  float S2 = red[4] + red[5] + red[6] + red[7];
  float m = S1 * (1.f / DIMQ);
  float var = S2 * (1.f / DIMQ) - m * m;
  float rs = rsqrtf(var + 1e-5f);
  float4 gv = *(const float4*)(g + d);
  float4 bv = *(const float4*)(beta + d);
  float4 o;
  o.x = (v0 - m) * rs * gv.x + bv.x;
  o.y = (v1 - m) * rs * gv.y + bv.y;
  o.z = (v2 - m) * rs * gv.z + bv.z;
  o.w = (v3 - m) * rs * gv.w + bv.w;
  *(float4*)(out + base) = o;
}

// ---------------- host launch ----------------
extern "C" void kernel_launch(void* const* d_in, const int* in_sizes, int n_in,
                              void* d_out, int out_size, void* d_ws, size_t ws_size,
                              hipStream_t stream) {
  const float* x     = (const float*)d_in[0];
  const int*   amask = (const int*)d_in[1];
  const float* Wq    = (const float*)d_in[2];
  const float* bq    = (const float*)d_in[3];
  const float* Wk    = (const float*)d_in[4];
  const float* bk    = (const float*)d_in[5];
  const float* Wv    = (const float*)d_in[6];
  const float* bv    = (const float*)d_in[7];
  const float* Wo    = (const float*)d_in[8];
  const float* bo    = (const float*)d_in[9];
  const float* g1    = (const float*)d_in[10];
  const float* beta1 = (const float*)d_in[11];
  const float* rw    = (const float*)d_in[12];
  const float* rb    = (const float*)d_in[13];
  const float* W1    = (const float*)d_in[14];
  const float* B1    = (const float*)d_in[15];
  const float* W2    = (const float*)d_in[16];
  const float* B2    = (const float*)d_in[17];
  const float* g2    = (const float*)d_in[18];
  const float* beta2 = (const float*)d_in[19];
  float* out    = (float*)d_out;
  float* lb_out = out + (size_t)NTOK * DIMQ;

  char* ws = (char*)d_ws;
  size_t off_acc = 0;
  auto alloc = [&](size_t bytes) {
    void* p = ws + off_acc;
    off_acc += (bytes + 255) & ~(size_t)255;
    return p;
  };
  u16* xb    = (u16*)alloc((size_t)NTOK * DIMQ * 2);
  u16* qbuf  = (u16*)alloc((size_t)NTOK * DIMQ * 2);
  u16* kbuf  = (u16*)alloc((size_t)NTOK * DIMQ * 2);
  u16* vbufT = (u16*)alloc((size_t)NTOK * DIMQ * 2);  // transposed: [col][row]
  u16* hb    = (u16*)alloc((size_t)NTOK * DIMQ * 2);
  u16* ho    = (u16*)alloc((size_t)NTOK * DIMQ * 2);
  float* x1  = (float*)alloc((size_t)NTOK * DIMQ * 4);
  u16* x1b   = (u16*)alloc((size_t)NTOK * DIMQ * 2);
  u16* Wqt   = (u16*)alloc((size_t)DIMQ * DIMQ * 2);
  u16* Wkt   = (u16*)alloc((size_t)DIMQ * DIMQ * 2);
  u16* Wvt   = (u16*)alloc((size_t)DIMQ * DIMQ * 2);
  u16* Wot   = (u16*)alloc((size_t)DIMQ * DIMQ * 2);
  u16* W1t   = (u16*)alloc((size_t)NEXP * DFF * DIMQ * 2);
  u16* W2t   = (u16*)alloc((size_t)NEXP * DIMQ * DFF * 2);
  u16* he    = (u16*)alloc((size_t)2 * NTOK * DFF * 2);
  u16* yslot = (u16*)alloc((size_t)2 * NTOK * DIMQ * 2);
  char* stats = (char*)alloc(4096);
  int*   cnt   = (int*)stats;
  float* Psum  = (float*)(stats + 32);
  int*   offp  = (int*)(stats + 64);
  int*   fill  = (int*)(stats + 96);
  int* topi    = (int*)alloc((size_t)NTOK * 2 * 4);
  float* gkbuf = (float*)alloc((size_t)NTOK * 2 * 4);
  int* posmap  = (int*)alloc((size_t)NTOK * 2 * 4);
  int* idxlist = (int*)alloc((size_t)NTOK * 2 * 4);
  float* probs = (float*)alloc((size_t)NTOK * 8 * 4);

  hipMemsetAsync(stats, 0, 64, stream);

  // converts / transposes
  cvt_f32_bf16<<<NTOK * DIMQ / 1024, 256, 0, stream>>>(x, xb, NTOK * DIMQ);
  transpose_f32_bf16<<<dim3(DIMQ / 32, DIMQ / 32, 1), 256, 0, stream>>>(Wq, Wqt, DIMQ, DIMQ);
  transpose_f32_bf16<<<dim3(DIMQ / 32, DIMQ / 32, 1), 256, 0, stream>>>(Wk, Wkt, DIMQ, DIMQ);
  transpose_f32_bf16<<<dim3(DIMQ / 32, DIMQ / 32, 1), 256, 0, stream>>>(Wv, Wvt, DIMQ, DIMQ);
  transpose_f32_bf16<<<dim3(DIMQ / 32, DIMQ / 32, 1), 256, 0, stream>>>(Wo, Wot, DIMQ, DIMQ);
  transpose_f32_bf16<<<dim3(DFF / 32, DIMQ / 32, NEXP), 256, 0, stream>>>(W1, W1t, DIMQ, DFF);
  transpose_f32_bf16<<<dim3(DIMQ / 32, DFF / 32, NEXP), 256, 0, stream>>>(W2, W2t, DFF, DIMQ);

  // attention path
  dim3 gproj(DIMQ / 128, NTOK / 128);
  gemm_bt_kernel<<<gproj, 256, 0, stream>>>(xb, Wqt, bq, qbuf, NTOK, DIMQ, DIMQ);
  gemm_bt_kernel<<<gproj, 256, 0, stream>>>(xb, Wkt, bk, kbuf, NTOK, DIMQ, DIMQ);
  gemm_bt_tc_kernel<<<gproj, 256, 0, stream>>>(xb, Wvt, bv, vbufT, NTOK, DIMQ, DIMQ);
  attn_mfma_kernel<<<dim3(TSEQ / 64, BATCH * NHEADS), 256, 0, stream>>>(qbuf, kbuf, vbufT, amask, hb);
  gemm_bt_kernel<<<gproj, 256, 0, stream>>>(hb, Wot, bo, ho, NTOK, DIMQ, DIMQ);
  addln_kernel<<<NTOK, 256, 0, stream>>>(x, ho, g1, beta1, x1, x1b);

  // MoE path
  router_kernel<<<NTOK / 4, 256, 0, stream>>>(x1, rw, rb, topi, gkbuf, probs);
  stats_kernel<<<NTOK / 256, 256, 0, stream>>>(probs, topi, cnt, Psum);
  offsets_kernel<<<1, 64, 0, stream>>>(cnt, Psum, offp, fill, lb_out);
  listbuild_kernel<<<NTOK / 256, 256, 0, stream>>>(topi, fill, idxlist, posmap);
  moe_gemm1_kernel<<<dim3(DFF / 256, 32, NEXP), 512, 0, stream>>>(x1b, W1t, B1, he, cnt, offp, idxlist);
  moe_gemm2_kernel<<<dim3(DIMQ / 256, 32, NEXP), 512, 0, stream>>>(he, W2t, B2, yslot, cnt, offp);
  finalln_kernel<<<NTOK, 256, 0, stream>>>(x1, yslot, posmap, gkbuf, g2, beta2, out);
}